// Round 1
// baseline (338.202 us; speedup 1.0000x reference)
//
#include <hip/hip_runtime.h>
#include <hip/hip_bf16.h>
#include <stdint.h>

typedef __attribute__((ext_vector_type(4))) float f32x4;
typedef __attribute__((ext_vector_type(8))) __bf16 bf16x8;
typedef __attribute__((ext_vector_type(4))) unsigned short us4;

#define SEQ 2048
#define DMODEL 1024
#define NH 16
#define DK 64
#define MTOT 4096  // B*SEQ

__device__ __forceinline__ unsigned short f2bf(float x) {
  union { float f; unsigned int u; } v; v.f = x;
  unsigned int r = v.u + 0x7fffu + ((v.u >> 16) & 1u);
  return (unsigned short)(r >> 16);
}

__device__ __forceinline__ f32x4 mfma_bf16(bf16x8 a, bf16x8 b, f32x4 c) {
  return __builtin_amdgcn_mfma_f32_16x16x32_bf16(a, b, c, 0, 0, 0);
}

__device__ __forceinline__ void gload16(const unsigned short* g, unsigned short* l) {
  __builtin_amdgcn_global_load_lds((__attribute__((address_space(1))) void*)g,
                                   (__attribute__((address_space(3))) void*)l,
                                   16, 0, 0);
}

// ---------------- fp32 -> bf16 conversion ----------------
__global__ void cvt3_kernel(const float* __restrict__ s0, const float* __restrict__ s1,
                            const float* __restrict__ s2,
                            unsigned short* __restrict__ d0, unsigned short* __restrict__ d1,
                            unsigned short* __restrict__ d2, int n4) {
  const float* s = blockIdx.y == 0 ? s0 : (blockIdx.y == 1 ? s1 : s2);
  unsigned short* d = blockIdx.y == 0 ? d0 : (blockIdx.y == 1 ? d1 : d2);
  int stride = gridDim.x * blockDim.x;
  for (int i = blockIdx.x * blockDim.x + threadIdx.x; i < n4; i += stride) {
    f32x4 v = reinterpret_cast<const f32x4*>(s)[i];
    us4 o;
    o.x = f2bf(v.x); o.y = f2bf(v.y); o.z = f2bf(v.z); o.w = f2bf(v.w);
    reinterpret_cast<us4*>(d)[i] = o;
  }
}

__global__ void cvt4_kernel(const float* __restrict__ s0, const float* __restrict__ s1,
                            const float* __restrict__ s2, const float* __restrict__ s3,
                            unsigned short* __restrict__ d0, unsigned short* __restrict__ d1,
                            unsigned short* __restrict__ d2, unsigned short* __restrict__ d3,
                            int n4) {
  const float* s = blockIdx.y == 0 ? s0 : blockIdx.y == 1 ? s1 : blockIdx.y == 2 ? s2 : s3;
  unsigned short* d = blockIdx.y == 0 ? d0 : blockIdx.y == 1 ? d1 : blockIdx.y == 2 ? d2 : d3;
  int stride = gridDim.x * blockDim.x;
  for (int i = blockIdx.x * blockDim.x + threadIdx.x; i < n4; i += stride) {
    f32x4 v = reinterpret_cast<const f32x4*>(s)[i];
    us4 o;
    o.x = f2bf(v.x); o.y = f2bf(v.y); o.z = f2bf(v.z); o.w = f2bf(v.w);
    reinterpret_cast<us4*>(d)[i] = o;
  }
}

// ---------------- GEMM: C[m,n] = sum_k A[m,k]*B[n,k], K=1024 ----------------
// MODE 0: bf16 out, head layout [bh][s][64], scaled
// MODE 1: bf16 out, V^T layout [bh][64][SEQ]
// MODE 2: f32 out row-major [M][1024]
template <int MODE>
__global__ __launch_bounds__(256) void gemm_bt(const unsigned short* __restrict__ A,
                                               const unsigned short* __restrict__ B,
                                               void* __restrict__ Cp, float scale) {
  __shared__ __align__(16) unsigned short lA[128 * 32];
  __shared__ __align__(16) unsigned short lB[128 * 32];
  const int tid = threadIdx.x;
  const int lane = tid & 63;
  const int wid = tid >> 6;
  const int l15 = lane & 15, l4 = lane >> 4;
  const int bm = blockIdx.x, bn = blockIdx.y;
  const int wr = wid >> 1, wc = wid & 1;

  f32x4 acc[4][4] = {};

  const int chunk0 = (wid * 2 + 0) * 64 + lane;
  const int chunk1 = (wid * 2 + 1) * 64 + lane;
  const unsigned short* gA0 = A + (size_t)(bm * 128 + (chunk0 >> 2)) * 1024 + (chunk0 & 3) * 8;
  const unsigned short* gA1 = A + (size_t)(bm * 128 + (chunk1 >> 2)) * 1024 + (chunk1 & 3) * 8;
  const unsigned short* gB0 = B + (size_t)(bn * 128 + (chunk0 >> 2)) * 1024 + (chunk0 & 3) * 8;
  const unsigned short* gB1 = B + (size_t)(bn * 128 + (chunk1 >> 2)) * 1024 + (chunk1 & 3) * 8;
  unsigned short* lA0 = lA + (wid * 2 + 0) * 512;
  unsigned short* lA1 = lA + (wid * 2 + 1) * 512;
  unsigned short* lB0 = lB + (wid * 2 + 0) * 512;
  unsigned short* lB1 = lB + (wid * 2 + 1) * 512;

  for (int kt = 0; kt < 1024; kt += 32) {
    __syncthreads();
    gload16(gA0 + kt, lA0);
    gload16(gA1 + kt, lA1);
    gload16(gB0 + kt, lB0);
    gload16(gB1 + kt, lB1);
    __syncthreads();
    bf16x8 af[4], bfr[4];
#pragma unroll
    for (int i = 0; i < 4; ++i)
      af[i] = *reinterpret_cast<const bf16x8*>(&lA[(wr * 64 + i * 16 + l15) * 32 + l4 * 8]);
#pragma unroll
    for (int j = 0; j < 4; ++j)
      bfr[j] = *reinterpret_cast<const bf16x8*>(&lB[(wc * 64 + j * 16 + l15) * 32 + l4 * 8]);
#pragma unroll
    for (int i = 0; i < 4; ++i)
#pragma unroll
      for (int j = 0; j < 4; ++j)
        acc[i][j] = mfma_bf16(af[i], bfr[j], acc[i][j]);
  }

  const int row0 = bm * 128 + wr * 64;
  const int col0 = bn * 128 + wc * 64;

  if constexpr (MODE == 0) {
    unsigned short* out = (unsigned short*)Cp;
#pragma unroll
    for (int i = 0; i < 4; ++i) {
#pragma unroll
      for (int j = 0; j < 4; ++j) {
        const int n = col0 + j * 16 + l15;
        const int h = n >> 6, d = n & 63;
#pragma unroll
        for (int r = 0; r < 4; ++r) {
          const int m = row0 + i * 16 + l4 * 4 + r;
          const int b = m >> 11, s = m & 2047;
          out[(size_t)(b * NH + h) * (SEQ * DK) + s * DK + d] = f2bf(acc[i][j][r] * scale);
        }
      }
    }
  } else if constexpr (MODE == 1) {
    unsigned short* out = (unsigned short*)Cp;
#pragma unroll
    for (int i = 0; i < 4; ++i) {
      const int m0 = row0 + i * 16 + l4 * 4;
      const int b = m0 >> 11, s0 = m0 & 2047;
#pragma unroll
      for (int j = 0; j < 4; ++j) {
        const int n = col0 + j * 16 + l15;
        const int h = n >> 6, d = n & 63;
        us4 pk;
        pk.x = f2bf(acc[i][j][0]);
        pk.y = f2bf(acc[i][j][1]);
        pk.z = f2bf(acc[i][j][2]);
        pk.w = f2bf(acc[i][j][3]);
        *reinterpret_cast<us4*>(&out[(size_t)(b * NH + h) * (DK * SEQ) + d * SEQ + s0]) = pk;
      }
    }
  } else {
    float* out = (float*)Cp;
#pragma unroll
    for (int i = 0; i < 4; ++i)
#pragma unroll
      for (int j = 0; j < 4; ++j)
#pragma unroll
        for (int r = 0; r < 4; ++r) {
          const int m = row0 + i * 16 + l4 * 4 + r;
          const int n = col0 + j * 16 + l15;
          out[(size_t)m * DMODEL + n] = acc[i][j][r];
        }
  }
}

// ---------------- causal flash attention ----------------
// Qh pre-scaled by 0.125*log2(e); softmax in exp2 domain.
// 1 wave per block; each block handles 16 q rows of one (b,h).
__global__ __launch_bounds__(64) void attn_kernel(const unsigned short* __restrict__ Qh,
                                                  const unsigned short* __restrict__ Kh,
                                                  const unsigned short* __restrict__ Vt,
                                                  unsigned short* __restrict__ Mg) {
  __shared__ __align__(16) unsigned short Plds[16 * 80];
  const int lane = threadIdx.x;
  const int l15 = lane & 15, l4 = lane >> 4;
  const int strip = (int)gridDim.x - 1 - (int)blockIdx.x;  // long strips first
  const int bh = blockIdx.y;
  const int q0 = strip * 16;

  const unsigned short* Qb = Qh + (size_t)bh * SEQ * DK;
  const unsigned short* Kb = Kh + (size_t)bh * SEQ * DK;
  const unsigned short* Vb = Vt + (size_t)bh * DK * SEQ;

  const unsigned short* qp = Qb + (size_t)(q0 + l15) * DK + l4 * 8;
  bf16x8 qf0 = *reinterpret_cast<const bf16x8*>(qp);
  bf16x8 qf1 = *reinterpret_cast<const bf16x8*>(qp + 32);

  f32x4 o[4] = {};
  float mrow[4], lrow[4];
#pragma unroll
  for (int r = 0; r < 4; ++r) { mrow[r] = -__builtin_inff(); lrow[r] = 0.0f; }

  const int ntiles = (q0 >> 6) + 1;
  for (int kt = 0; kt < ntiles; ++kt) {
    const int kbase = kt << 6;
    // ---- S = Q K^T (log2-domain) ----
    f32x4 sc[4];
#pragma unroll
    for (int c = 0; c < 4; ++c) {
      const unsigned short* kp = Kb + (size_t)(kbase + c * 16 + l15) * DK + l4 * 8;
      bf16x8 kf0 = *reinterpret_cast<const bf16x8*>(kp);
      bf16x8 kf1 = *reinterpret_cast<const bf16x8*>(kp + 32);
      f32x4 z = {0.f, 0.f, 0.f, 0.f};
      z = mfma_bf16(qf0, kf0, z);
      sc[c] = mfma_bf16(qf1, kf1, z);
    }
    // ---- causal mask (only the diagonal tile needs it) ----
    if (kt == ntiles - 1) {
#pragma unroll
      for (int c = 0; c < 4; ++c) {
        const int col = kbase + c * 16 + l15;
#pragma unroll
        for (int r = 0; r < 4; ++r) {
          const int row = q0 + l4 * 4 + r;
          if (col > row) sc[c][r] = -__builtin_inff();
        }
      }
    }
    // ---- online softmax ----
    float pm[4];
#pragma unroll
    for (int r = 0; r < 4; ++r)
      pm[r] = fmaxf(fmaxf(sc[0][r], sc[1][r]), fmaxf(sc[2][r], sc[3][r]));
#pragma unroll
    for (int r = 0; r < 4; ++r) {
      pm[r] = fmaxf(pm[r], __shfl_xor(pm[r], 1));
      pm[r] = fmaxf(pm[r], __shfl_xor(pm[r], 2));
      pm[r] = fmaxf(pm[r], __shfl_xor(pm[r], 4));
      pm[r] = fmaxf(pm[r], __shfl_xor(pm[r], 8));
    }
    float al[4], rs[4];
#pragma unroll
    for (int r = 0; r < 4; ++r) {
      const float mn = fmaxf(mrow[r], pm[r]);
      al[r] = __builtin_amdgcn_exp2f(mrow[r] - mn);
      mrow[r] = mn;
      float p0 = __builtin_amdgcn_exp2f(sc[0][r] - mn);
      float p1 = __builtin_amdgcn_exp2f(sc[1][r] - mn);
      float p2 = __builtin_amdgcn_exp2f(sc[2][r] - mn);
      float p3 = __builtin_amdgcn_exp2f(sc[3][r] - mn);
      sc[0][r] = p0; sc[1][r] = p1; sc[2][r] = p2; sc[3][r] = p3;
      rs[r] = (p0 + p1) + (p2 + p3);
    }
#pragma unroll
    for (int r = 0; r < 4; ++r) {
      rs[r] += __shfl_xor(rs[r], 1);
      rs[r] += __shfl_xor(rs[r], 2);
      rs[r] += __shfl_xor(rs[r], 4);
      rs[r] += __shfl_xor(rs[r], 8);
      lrow[r] = lrow[r] * al[r] + rs[r];
    }
#pragma unroll
    for (int c = 0; c < 4; ++c)
#pragma unroll
      for (int r = 0; r < 4; ++r)
        o[c][r] *= al[r];
    // ---- P through LDS (C-layout -> A-fragment layout) ----
#pragma unroll
    for (int c = 0; c < 4; ++c)
#pragma unroll
      for (int r = 0; r < 4; ++r)
        Plds[(l4 * 4 + r) * 80 + c * 16 + l15] = f2bf(sc[c][r]);
    __syncthreads();
    bf16x8 pa0 = *reinterpret_cast<const bf16x8*>(&Plds[l15 * 80 + l4 * 8]);
    bf16x8 pa1 = *reinterpret_cast<const bf16x8*>(&Plds[l15 * 80 + 32 + l4 * 8]);
    // ---- O += P V ----
#pragma unroll
    for (int c = 0; c < 4; ++c) {
      const unsigned short* vp = Vb + (size_t)(c * 16 + l15) * SEQ + kbase + l4 * 8;
      bf16x8 v0 = *reinterpret_cast<const bf16x8*>(vp);
      bf16x8 v1 = *reinterpret_cast<const bf16x8*>(vp + 32);
      o[c] = mfma_bf16(pa0, v0, o[c]);
      o[c] = mfma_bf16(pa1, v1, o[c]);
    }
  }

  // ---- epilogue: normalize, write merged [b][s][h*64+d] bf16 ----
  const int bq = bh >> 4, hh = bh & 15;
  float inv[4];
#pragma unroll
  for (int r = 0; r < 4; ++r) inv[r] = __builtin_amdgcn_rcpf(lrow[r]);
#pragma unroll
  for (int c = 0; c < 4; ++c)
#pragma unroll
    for (int r = 0; r < 4; ++r) {
      const int s = q0 + l4 * 4 + r;
      Mg[(size_t)(bq * SEQ + s) * DMODEL + hh * DK + c * 16 + l15] = f2bf(o[c][r] * inv[r]);
    }
}

extern "C" void kernel_launch(void* const* d_in, const int* in_sizes, int n_in,
                              void* d_out, int out_size, void* d_ws, size_t ws_size,
                              hipStream_t stream) {
  (void)in_sizes; (void)n_in; (void)out_size;
  if (ws_size < (size_t)64 * (1 << 20)) return;  // need 64MB scratch

  const float* q = (const float*)d_in[0];
  const float* k = (const float*)d_in[1];
  const float* v = (const float*)d_in[2];
  // d_in[3] = mask (causal, hardcoded)
  const float* wq = (const float*)d_in[4];
  const float* wk = (const float*)d_in[5];
  const float* wv = (const float*)d_in[6];
  const float* wo = (const float*)d_in[7];

  char* ws = (char*)d_ws;
  unsigned short* xq  = (unsigned short*)(ws + (size_t)0  * (1 << 20));
  unsigned short* xk  = (unsigned short*)(ws + (size_t)8  * (1 << 20));
  unsigned short* xv  = (unsigned short*)(ws + (size_t)16 * (1 << 20));
  unsigned short* bwq = (unsigned short*)(ws + (size_t)24 * (1 << 20));
  unsigned short* bwk = (unsigned short*)(ws + (size_t)26 * (1 << 20));
  unsigned short* bwv = (unsigned short*)(ws + (size_t)28 * (1 << 20));
  unsigned short* bwo = (unsigned short*)(ws + (size_t)30 * (1 << 20));
  unsigned short* Qh  = (unsigned short*)(ws + (size_t)32 * (1 << 20));
  unsigned short* Kh  = (unsigned short*)(ws + (size_t)40 * (1 << 20));
  unsigned short* Vt  = (unsigned short*)(ws + (size_t)48 * (1 << 20));
  unsigned short* Mg  = (unsigned short*)(ws + (size_t)56 * (1 << 20));

  cvt3_kernel<<<dim3(512, 3), 256, 0, stream>>>(q, k, v, xq, xk, xv, (MTOT * DMODEL) / 4);
  cvt4_kernel<<<dim3(256, 4), 256, 0, stream>>>(wq, wk, wv, wo, bwq, bwk, bwv, bwo,
                                                (DMODEL * DMODEL) / 4);
  dim3 gg(32, 8);
  // Q pre-scaled by (1/sqrt(64)) * log2(e) so softmax uses exp2 directly
  gemm_bt<0><<<gg, 256, 0, stream>>>(xq, bwq, Qh, 0.18033688011112042f);
  gemm_bt<0><<<gg, 256, 0, stream>>>(xk, bwk, Kh, 1.0f);
  gemm_bt<1><<<gg, 256, 0, stream>>>(xv, bwv, Vt, 1.0f);
  attn_kernel<<<dim3(128, 32), 64, 0, stream>>>(Qh, Kh, Vt, Mg);
  gemm_bt<2><<<gg, 256, 0, stream>>>(Mg, bwo, d_out, 1.0f);
}

// Round 2
// 282.969 us; speedup vs baseline: 1.1952x; 1.1952x over previous
//
#include <hip/hip_runtime.h>
#include <hip/hip_bf16.h>
#include <stdint.h>

typedef __attribute__((ext_vector_type(4))) float f32x4;
typedef __attribute__((ext_vector_type(8))) __bf16 bf16x8;
typedef __attribute__((ext_vector_type(4))) unsigned short us4;
typedef __attribute__((ext_vector_type(4))) short v4ss;

#define SEQ 2048
#define DMODEL 1024
#define NH 16
#define DK 64
#define MTOT 4096  // B*SEQ

__device__ __forceinline__ unsigned short f2bf(float x) {
  union { float f; unsigned int u; } v; v.f = x;
  unsigned int r = v.u + 0x7fffu + ((v.u >> 16) & 1u);
  return (unsigned short)(r >> 16);
}

__device__ __forceinline__ f32x4 mfma_bf16(bf16x8 a, bf16x8 b, f32x4 c) {
  return __builtin_amdgcn_mfma_f32_16x16x32_bf16(a, b, c, 0, 0, 0);
}

// K=16 MFMA: D[m][n] += sum_{k=0..15} A[m][k]*B[n][k]
// operand layout: lane holds row m|n = lane&15, k = (lane>>4)*4 + j (j=elem 0..3)
__device__ __forceinline__ f32x4 mfma_k16(us4 a, us4 b, f32x4 c) {
#if __has_builtin(__builtin_amdgcn_mfma_f32_16x16x16bf16_1k)
  return __builtin_amdgcn_mfma_f32_16x16x16bf16_1k(
      __builtin_bit_cast(v4ss, a), __builtin_bit_cast(v4ss, b), c, 0, 0, 0);
#else
  // exact emulation on K=32 path: values at elems 0..3 are k_eff=(lane>>4)*8+j on
  // BOTH operands -> pairs A_true[m][l4*4+j] with B_true[n][l4*4+j]; zeros add 0.
  union U { bf16x8 v; us4 h[2]; } ua, ub;
  us4 z = {0, 0, 0, 0};
  ua.h[0] = a; ua.h[1] = z;
  ub.h[0] = b; ub.h[1] = z;
  return mfma_bf16(ua.v, ub.v, c);
#endif
}

__device__ __forceinline__ void gload16(const unsigned short* g, unsigned short* l) {
  __builtin_amdgcn_global_load_lds((__attribute__((address_space(1))) void*)g,
                                   (__attribute__((address_space(3))) void*)l,
                                   16, 0, 0);
}

// ---------------- fp32 -> bf16 conversion ----------------
__global__ void cvt3_kernel(const float* __restrict__ s0, const float* __restrict__ s1,
                            const float* __restrict__ s2,
                            unsigned short* __restrict__ d0, unsigned short* __restrict__ d1,
                            unsigned short* __restrict__ d2, int n4) {
  const float* s = blockIdx.y == 0 ? s0 : (blockIdx.y == 1 ? s1 : s2);
  unsigned short* d = blockIdx.y == 0 ? d0 : (blockIdx.y == 1 ? d1 : d2);
  int stride = gridDim.x * blockDim.x;
  for (int i = blockIdx.x * blockDim.x + threadIdx.x; i < n4; i += stride) {
    f32x4 v = reinterpret_cast<const f32x4*>(s)[i];
    us4 o;
    o.x = f2bf(v.x); o.y = f2bf(v.y); o.z = f2bf(v.z); o.w = f2bf(v.w);
    reinterpret_cast<us4*>(d)[i] = o;
  }
}

__global__ void cvt4_kernel(const float* __restrict__ s0, const float* __restrict__ s1,
                            const float* __restrict__ s2, const float* __restrict__ s3,
                            unsigned short* __restrict__ d0, unsigned short* __restrict__ d1,
                            unsigned short* __restrict__ d2, unsigned short* __restrict__ d3,
                            int n4) {
  const float* s = blockIdx.y == 0 ? s0 : blockIdx.y == 1 ? s1 : blockIdx.y == 2 ? s2 : s3;
  unsigned short* d = blockIdx.y == 0 ? d0 : blockIdx.y == 1 ? d1 : blockIdx.y == 2 ? d2 : d3;
  int stride = gridDim.x * blockDim.x;
  for (int i = blockIdx.x * blockDim.x + threadIdx.x; i < n4; i += stride) {
    f32x4 v = reinterpret_cast<const f32x4*>(s)[i];
    us4 o;
    o.x = f2bf(v.x); o.y = f2bf(v.y); o.z = f2bf(v.z); o.w = f2bf(v.w);
    reinterpret_cast<us4*>(d)[i] = o;
  }
}

// ---------------- GEMM: C[m,n] = sum_k A[m,k]*B[n,k], K=1024 ----------------
template <int MODE>
__global__ __launch_bounds__(256) void gemm_bt(const unsigned short* __restrict__ A,
                                               const unsigned short* __restrict__ B,
                                               void* __restrict__ Cp, float scale) {
  __shared__ __align__(16) unsigned short lA[128 * 32];
  __shared__ __align__(16) unsigned short lB[128 * 32];
  const int tid = threadIdx.x;
  const int lane = tid & 63;
  const int wid = tid >> 6;
  const int l15 = lane & 15, l4 = lane >> 4;
  const int bm = blockIdx.x, bn = blockIdx.y;
  const int wr = wid >> 1, wc = wid & 1;

  f32x4 acc[4][4] = {};

  const int chunk0 = (wid * 2 + 0) * 64 + lane;
  const int chunk1 = (wid * 2 + 1) * 64 + lane;
  const unsigned short* gA0 = A + (size_t)(bm * 128 + (chunk0 >> 2)) * 1024 + (chunk0 & 3) * 8;
  const unsigned short* gA1 = A + (size_t)(bm * 128 + (chunk1 >> 2)) * 1024 + (chunk1 & 3) * 8;
  const unsigned short* gB0 = B + (size_t)(bn * 128 + (chunk0 >> 2)) * 1024 + (chunk0 & 3) * 8;
  const unsigned short* gB1 = B + (size_t)(bn * 128 + (chunk1 >> 2)) * 1024 + (chunk1 & 3) * 8;
  unsigned short* lA0 = lA + (wid * 2 + 0) * 512;
  unsigned short* lA1 = lA + (wid * 2 + 1) * 512;
  unsigned short* lB0 = lB + (wid * 2 + 0) * 512;
  unsigned short* lB1 = lB + (wid * 2 + 1) * 512;

  for (int kt = 0; kt < 1024; kt += 32) {
    __syncthreads();
    gload16(gA0 + kt, lA0);
    gload16(gA1 + kt, lA1);
    gload16(gB0 + kt, lB0);
    gload16(gB1 + kt, lB1);
    __syncthreads();
    bf16x8 af[4], bfr[4];
#pragma unroll
    for (int i = 0; i < 4; ++i)
      af[i] = *reinterpret_cast<const bf16x8*>(&lA[(wr * 64 + i * 16 + l15) * 32 + l4 * 8]);
#pragma unroll
    for (int j = 0; j < 4; ++j)
      bfr[j] = *reinterpret_cast<const bf16x8*>(&lB[(wc * 64 + j * 16 + l15) * 32 + l4 * 8]);
#pragma unroll
    for (int i = 0; i < 4; ++i)
#pragma unroll
      for (int j = 0; j < 4; ++j)
        acc[i][j] = mfma_bf16(af[i], bfr[j], acc[i][j]);
  }

  const int row0 = bm * 128 + wr * 64;
  const int col0 = bn * 128 + wc * 64;

  if constexpr (MODE == 0) {
    unsigned short* out = (unsigned short*)Cp;
#pragma unroll
    for (int i = 0; i < 4; ++i) {
#pragma unroll
      for (int j = 0; j < 4; ++j) {
        const int n = col0 + j * 16 + l15;
        const int h = n >> 6, d = n & 63;
#pragma unroll
        for (int r = 0; r < 4; ++r) {
          const int m = row0 + i * 16 + l4 * 4 + r;
          const int b = m >> 11, s = m & 2047;
          out[(size_t)(b * NH + h) * (SEQ * DK) + s * DK + d] = f2bf(acc[i][j][r] * scale);
        }
      }
    }
  } else if constexpr (MODE == 1) {
    unsigned short* out = (unsigned short*)Cp;
#pragma unroll
    for (int i = 0; i < 4; ++i) {
      const int m0 = row0 + i * 16 + l4 * 4;
      const int b = m0 >> 11, s0 = m0 & 2047;
#pragma unroll
      for (int j = 0; j < 4; ++j) {
        const int n = col0 + j * 16 + l15;
        const int h = n >> 6, d = n & 63;
        us4 pk;
        pk.x = f2bf(acc[i][j][0]);
        pk.y = f2bf(acc[i][j][1]);
        pk.z = f2bf(acc[i][j][2]);
        pk.w = f2bf(acc[i][j][3]);
        *reinterpret_cast<us4*>(&out[(size_t)(b * NH + h) * (DK * SEQ) + d * SEQ + s0]) = pk;
      }
    }
  } else {
    float* out = (float*)Cp;
#pragma unroll
    for (int i = 0; i < 4; ++i)
#pragma unroll
      for (int j = 0; j < 4; ++j)
#pragma unroll
        for (int r = 0; r < 4; ++r) {
          const int m = row0 + i * 16 + l4 * 4 + r;
          const int n = col0 + j * 16 + l15;
          out[(size_t)m * DMODEL + n] = acc[i][j][r];
        }
  }
}

// ---------------- causal flash attention, swapped-QK^T, LDS-free ----------------
// Per wave: 32 q rows (2 groups of 16). S^T = mfma(K, Q): lane l15 = q, holds
// kpos = (lane>>4)*4 + r per 16-kpos subtile -> softmax is in-lane tree +
// shfl_xor(16,32); P^T C-layout == B-frag of K=16 MFMA -> PV (O^T = V^T * P)
// needs no LDS and no shuffles. K-tile double-buffered in registers.
__global__ __launch_bounds__(64, 2) void attn_kernel(const unsigned short* __restrict__ Qh,
                                                     const unsigned short* __restrict__ Kh,
                                                     const unsigned short* __restrict__ Vt,
                                                     unsigned short* __restrict__ Mg) {
  const int lane = threadIdx.x & 63;
  const int l15 = lane & 15, l4 = lane >> 4;
  const int strip = (int)gridDim.x - 1 - (int)blockIdx.x;  // long strips dispatch first
  const int bh = blockIdx.y;
  const int q0 = strip * 32;

  const unsigned short* Qb = Qh + (size_t)bh * SEQ * DK;
  const unsigned short* Kb = Kh + (size_t)bh * SEQ * DK;
  const unsigned short* Vb = Vt + (size_t)bh * DK * SEQ;

  // Q as B-fragment: lane l15 = q row, k(dk) = l4*8
  bf16x8 qf[2][2];
#pragma unroll
  for (int g = 0; g < 2; ++g)
#pragma unroll
    for (int h = 0; h < 2; ++h)
      qf[g][h] = *reinterpret_cast<const bf16x8*>(Qb + (q0 + 16 * g + l15) * DK + h * 32 + l4 * 8);

  f32x4 o[2][4] = {};  // O^T accum: [g][d-subtile]; col=l15=q, row d = l4*4+reg
  float mrow[2], lrow[2];
  mrow[0] = mrow[1] = -__builtin_inff();
  lrow[0] = lrow[1] = 0.0f;

  const int nt = (q0 >> 6) + 1;

  // K as A-fragment: lane l15 = kpos row, k(dk) = l4*8. Preload tile 0.
  bf16x8 kf[4][2];
#pragma unroll
  for (int c = 0; c < 4; ++c)
#pragma unroll
    for (int h = 0; h < 2; ++h)
      kf[c][h] = *reinterpret_cast<const bf16x8*>(Kb + (c * 16 + l15) * DK + h * 32 + l4 * 8);

  for (int kt = 0; kt < nt; ++kt) {
    const int kbase = kt << 6;

    // ---- V^T A-fragments for this tile (issued early, consumed after softmax) ----
    us4 va[4][4];  // [d-subtile][kpos-subtile]: V^T[dd*16+l15][kbase+c*16+l4*4 ..+3]
#pragma unroll
    for (int dd = 0; dd < 4; ++dd)
#pragma unroll
      for (int c = 0; c < 4; ++c)
        va[dd][c] = *reinterpret_cast<const us4*>(Vb + (dd * 16 + l15) * SEQ + kbase + c * 16 + l4 * 4);

    // ---- S^T = K Q^T (log2 domain; Q pre-scaled) ----
    f32x4 sc[2][4];  // [g][kpos-subtile]; lane: q=l15, kpos=kbase+c*16+l4*4+r
#pragma unroll
    for (int c = 0; c < 4; ++c)
#pragma unroll
      for (int g = 0; g < 2; ++g) {
        f32x4 z = {0.f, 0.f, 0.f, 0.f};
        z = mfma_bf16(kf[c][0], qf[g][0], z);
        sc[g][c] = mfma_bf16(kf[c][1], qf[g][1], z);
      }

    // ---- prefetch next K tile into kn while softmax runs ----
    const int kb2 = (kt + 1 < nt) ? kbase + 64 : kbase;
    bf16x8 kn[4][2];
#pragma unroll
    for (int c = 0; c < 4; ++c)
#pragma unroll
      for (int h = 0; h < 2; ++h)
        kn[c][h] = *reinterpret_cast<const bf16x8*>(Kb + (kb2 + c * 16 + l15) * DK + h * 32 + l4 * 8);

    // ---- causal mask (last tile only) ----
    if (kt == nt - 1) {
#pragma unroll
      for (int g = 0; g < 2; ++g) {
        const int qg = q0 + 16 * g + l15;
#pragma unroll
        for (int c = 0; c < 4; ++c) {
          const int kp = kbase + c * 16 + l4 * 4;
#pragma unroll
          for (int r = 0; r < 4; ++r)
            if (kp + r > qg) sc[g][c][r] = -__builtin_inff();
        }
      }
    }

    // ---- online softmax (per g; all cross-lane over l4 groups only) ----
    us4 pb[2][4];  // packed P: B-frag of K=16 MFMA
#pragma unroll
    for (int g = 0; g < 2; ++g) {
      f32x4 mv = sc[g][0];
#pragma unroll
      for (int c = 1; c < 4; ++c)
#pragma unroll
        for (int r = 0; r < 4; ++r) mv[r] = fmaxf(mv[r], sc[g][c][r]);
      float pm = fmaxf(fmaxf(mv[0], mv[1]), fmaxf(mv[2], mv[3]));
      pm = fmaxf(pm, __shfl_xor(pm, 16));
      pm = fmaxf(pm, __shfl_xor(pm, 32));
      const float mn = fmaxf(mrow[g], pm);
      const float al = __builtin_amdgcn_exp2f(mrow[g] - mn);
      mrow[g] = mn;
      f32x4 sv = {0.f, 0.f, 0.f, 0.f};
#pragma unroll
      for (int c = 0; c < 4; ++c) {
#pragma unroll
        for (int r = 0; r < 4; ++r) {
          const float p = __builtin_amdgcn_exp2f(sc[g][c][r] - mn);
          sc[g][c][r] = p;
          sv[r] += p;
        }
        us4 pk;
        pk.x = f2bf(sc[g][c][0]);
        pk.y = f2bf(sc[g][c][1]);
        pk.z = f2bf(sc[g][c][2]);
        pk.w = f2bf(sc[g][c][3]);
        pb[g][c] = pk;
      }
      float rs = (sv[0] + sv[1]) + (sv[2] + sv[3]);
      rs += __shfl_xor(rs, 16);
      rs += __shfl_xor(rs, 32);
      lrow[g] = lrow[g] * al + rs;
#pragma unroll
      for (int dd = 0; dd < 4; ++dd)
#pragma unroll
        for (int r = 0; r < 4; ++r) o[g][dd][r] *= al;
    }

    // ---- O^T += V^T P  (K=16 MFMAs; P consumed straight from registers) ----
#pragma unroll
    for (int g = 0; g < 2; ++g)
#pragma unroll
      for (int dd = 0; dd < 4; ++dd)
#pragma unroll
        for (int c = 0; c < 4; ++c)
          o[g][dd] = mfma_k16(va[dd][c], pb[g][c], o[g][dd]);

    // rotate K double-buffer
#pragma unroll
    for (int c = 0; c < 4; ++c)
#pragma unroll
      for (int h = 0; h < 2; ++h)
        kf[c][h] = kn[c][h];
  }

  // ---- epilogue: normalize, write merged [b][s][h*64+d] bf16 (8B stores) ----
  const int bq = bh >> 4, hh = bh & 15;
  unsigned short* Mbase = Mg + (size_t)bq * SEQ * DMODEL + hh * DK;
#pragma unroll
  for (int g = 0; g < 2; ++g) {
    const float inv = __builtin_amdgcn_rcpf(lrow[g]);
    const int s = q0 + 16 * g + l15;
#pragma unroll
    for (int dd = 0; dd < 4; ++dd) {
      us4 pk;
      pk.x = f2bf(o[g][dd][0] * inv);
      pk.y = f2bf(o[g][dd][1] * inv);
      pk.z = f2bf(o[g][dd][2] * inv);
      pk.w = f2bf(o[g][dd][3] * inv);
      *reinterpret_cast<us4*>(&Mbase[(size_t)s * DMODEL + dd * 16 + l4 * 4]) = pk;
    }
  }
}

extern "C" void kernel_launch(void* const* d_in, const int* in_sizes, int n_in,
                              void* d_out, int out_size, void* d_ws, size_t ws_size,
                              hipStream_t stream) {
  (void)in_sizes; (void)n_in; (void)out_size;
  if (ws_size < (size_t)64 * (1 << 20)) return;  // need 64MB scratch

  const float* q = (const float*)d_in[0];
  const float* k = (const float*)d_in[1];
  const float* v = (const float*)d_in[2];
  // d_in[3] = mask (causal, hardcoded)
  const float* wq = (const float*)d_in[4];
  const float* wk = (const float*)d_in[5];
  const float* wv = (const float*)d_in[6];
  const float* wo = (const float*)d_in[7];

  char* ws = (char*)d_ws;
  unsigned short* xq  = (unsigned short*)(ws + (size_t)0  * (1 << 20));
  unsigned short* xk  = (unsigned short*)(ws + (size_t)8  * (1 << 20));
  unsigned short* xv  = (unsigned short*)(ws + (size_t)16 * (1 << 20));
  unsigned short* bwq = (unsigned short*)(ws + (size_t)24 * (1 << 20));
  unsigned short* bwk = (unsigned short*)(ws + (size_t)26 * (1 << 20));
  unsigned short* bwv = (unsigned short*)(ws + (size_t)28 * (1 << 20));
  unsigned short* bwo = (unsigned short*)(ws + (size_t)30 * (1 << 20));
  unsigned short* Qh  = (unsigned short*)(ws + (size_t)32 * (1 << 20));
  unsigned short* Kh  = (unsigned short*)(ws + (size_t)40 * (1 << 20));
  unsigned short* Vt  = (unsigned short*)(ws + (size_t)48 * (1 << 20));
  unsigned short* Mg  = (unsigned short*)(ws + (size_t)56 * (1 << 20));

  cvt3_kernel<<<dim3(512, 3), 256, 0, stream>>>(q, k, v, xq, xk, xv, (MTOT * DMODEL) / 4);
  cvt4_kernel<<<dim3(256, 4), 256, 0, stream>>>(wq, wk, wv, wo, bwq, bwk, bwv, bwo,
                                                (DMODEL * DMODEL) / 4);
  dim3 gg(32, 8);
  // Q pre-scaled by (1/sqrt(64)) * log2(e) so softmax uses exp2 directly
  gemm_bt<0><<<gg, 256, 0, stream>>>(xq, bwq, Qh, 0.18033688011112042f);
  gemm_bt<0><<<gg, 256, 0, stream>>>(xk, bwk, Kh, 1.0f);
  gemm_bt<1><<<gg, 256, 0, stream>>>(xv, bwv, Vt, 1.0f);
  attn_kernel<<<dim3(64, 32), 64, 0, stream>>>(Qh, Kh, Vt, Mg);
  gemm_bt<2><<<gg, 256, 0, stream>>>(Mg, bwo, d_out, 1.0f);
}

// Round 3
// 167.583 us; speedup vs baseline: 2.0181x; 1.6885x over previous
//
#include <hip/hip_runtime.h>
#include <hip/hip_bf16.h>
#include <stdint.h>

typedef __attribute__((ext_vector_type(4))) float f32x4;
typedef __attribute__((ext_vector_type(8))) __bf16 bf16x8;
typedef __attribute__((ext_vector_type(4))) unsigned short us4;
typedef __attribute__((ext_vector_type(4))) short v4ss;

#define SEQ 2048
#define DMODEL 1024
#define NH 16
#define DK 64
#define MTOT 4096  // B*SEQ

__device__ __forceinline__ unsigned short f2bf(float x) {
  union { float f; unsigned int u; } v; v.f = x;
  unsigned int r = v.u + 0x7fffu + ((v.u >> 16) & 1u);
  return (unsigned short)(r >> 16);
}

__device__ __forceinline__ f32x4 mfma_bf16(bf16x8 a, bf16x8 b, f32x4 c) {
  return __builtin_amdgcn_mfma_f32_16x16x32_bf16(a, b, c, 0, 0, 0);
}

// K=16 MFMA: D[m][n] += sum_{k=0..15} A[m][k]*B[n][k]
// lane holds row m|n = lane&15, k = (lane>>4)*4 + j (j=0..3)
__device__ __forceinline__ f32x4 mfma_k16(us4 a, us4 b, f32x4 c) {
#if __has_builtin(__builtin_amdgcn_mfma_f32_16x16x16bf16_1k)
  return __builtin_amdgcn_mfma_f32_16x16x16bf16_1k(
      __builtin_bit_cast(v4ss, a), __builtin_bit_cast(v4ss, b), c, 0, 0, 0);
#else
  // exact emulation on K=32: zeros in upper half contribute 0
  union U { bf16x8 v; us4 h[2]; } ua, ub;
  us4 z = {0, 0, 0, 0};
  ua.h[0] = a; ua.h[1] = z;
  ub.h[0] = b; ub.h[1] = z;
  return mfma_bf16(ua.v, ub.v, c);
#endif
}

__device__ __forceinline__ void gload16(const unsigned short* g, unsigned short* l) {
  __builtin_amdgcn_global_load_lds((__attribute__((address_space(1))) void*)g,
                                   (__attribute__((address_space(3))) void*)l,
                                   16, 0, 0);
}

// ---------------- fp32 -> bf16 conversion ----------------
__global__ void cvt3_kernel(const float* __restrict__ s0, const float* __restrict__ s1,
                            const float* __restrict__ s2,
                            unsigned short* __restrict__ d0, unsigned short* __restrict__ d1,
                            unsigned short* __restrict__ d2, int n4) {
  const float* s = blockIdx.y == 0 ? s0 : (blockIdx.y == 1 ? s1 : s2);
  unsigned short* d = blockIdx.y == 0 ? d0 : (blockIdx.y == 1 ? d1 : d2);
  int stride = gridDim.x * blockDim.x;
  for (int i = blockIdx.x * blockDim.x + threadIdx.x; i < n4; i += stride) {
    f32x4 v = reinterpret_cast<const f32x4*>(s)[i];
    us4 o;
    o.x = f2bf(v.x); o.y = f2bf(v.y); o.z = f2bf(v.z); o.w = f2bf(v.w);
    reinterpret_cast<us4*>(d)[i] = o;
  }
}

__global__ void cvt4_kernel(const float* __restrict__ s0, const float* __restrict__ s1,
                            const float* __restrict__ s2, const float* __restrict__ s3,
                            unsigned short* __restrict__ d0, unsigned short* __restrict__ d1,
                            unsigned short* __restrict__ d2, unsigned short* __restrict__ d3,
                            int n4) {
  const float* s = blockIdx.y == 0 ? s0 : blockIdx.y == 1 ? s1 : blockIdx.y == 2 ? s2 : s3;
  unsigned short* d = blockIdx.y == 0 ? d0 : blockIdx.y == 1 ? d1 : blockIdx.y == 2 ? d2 : d3;
  int stride = gridDim.x * blockDim.x;
  for (int i = blockIdx.x * blockDim.x + threadIdx.x; i < n4; i += stride) {
    f32x4 v = reinterpret_cast<const f32x4*>(s)[i];
    us4 o;
    o.x = f2bf(v.x); o.y = f2bf(v.y); o.z = f2bf(v.z); o.w = f2bf(v.w);
    reinterpret_cast<us4*>(d)[i] = o;
  }
}

// ---------------- GEMM: C[m,n] = sum_k A[m,k]*B[n,k], K=1024 ----------------
template <int MODE>
__global__ __launch_bounds__(256) void gemm_bt(const unsigned short* __restrict__ A,
                                               const unsigned short* __restrict__ B,
                                               void* __restrict__ Cp, float scale) {
  __shared__ __align__(16) unsigned short lA[128 * 32];
  __shared__ __align__(16) unsigned short lB[128 * 32];
  const int tid = threadIdx.x;
  const int lane = tid & 63;
  const int wid = tid >> 6;
  const int l15 = lane & 15, l4 = lane >> 4;
  const int bm = blockIdx.x, bn = blockIdx.y;
  const int wr = wid >> 1, wc = wid & 1;

  f32x4 acc[4][4] = {};

  const int chunk0 = (wid * 2 + 0) * 64 + lane;
  const int chunk1 = (wid * 2 + 1) * 64 + lane;
  const unsigned short* gA0 = A + (size_t)(bm * 128 + (chunk0 >> 2)) * 1024 + (chunk0 & 3) * 8;
  const unsigned short* gA1 = A + (size_t)(bm * 128 + (chunk1 >> 2)) * 1024 + (chunk1 & 3) * 8;
  const unsigned short* gB0 = B + (size_t)(bn * 128 + (chunk0 >> 2)) * 1024 + (chunk0 & 3) * 8;
  const unsigned short* gB1 = B + (size_t)(bn * 128 + (chunk1 >> 2)) * 1024 + (chunk1 & 3) * 8;
  unsigned short* lA0 = lA + (wid * 2 + 0) * 512;
  unsigned short* lA1 = lA + (wid * 2 + 1) * 512;
  unsigned short* lB0 = lB + (wid * 2 + 0) * 512;
  unsigned short* lB1 = lB + (wid * 2 + 1) * 512;

  for (int kt = 0; kt < 1024; kt += 32) {
    __syncthreads();
    gload16(gA0 + kt, lA0);
    gload16(gA1 + kt, lA1);
    gload16(gB0 + kt, lB0);
    gload16(gB1 + kt, lB1);
    __syncthreads();
    bf16x8 af[4], bfr[4];
#pragma unroll
    for (int i = 0; i < 4; ++i)
      af[i] = *reinterpret_cast<const bf16x8*>(&lA[(wr * 64 + i * 16 + l15) * 32 + l4 * 8]);
#pragma unroll
    for (int j = 0; j < 4; ++j)
      bfr[j] = *reinterpret_cast<const bf16x8*>(&lB[(wc * 64 + j * 16 + l15) * 32 + l4 * 8]);
#pragma unroll
    for (int i = 0; i < 4; ++i)
#pragma unroll
      for (int j = 0; j < 4; ++j)
        acc[i][j] = mfma_bf16(af[i], bfr[j], acc[i][j]);
  }

  const int row0 = bm * 128 + wr * 64;
  const int col0 = bn * 128 + wc * 64;

  if constexpr (MODE == 0) {
    unsigned short* out = (unsigned short*)Cp;
#pragma unroll
    for (int i = 0; i < 4; ++i) {
#pragma unroll
      for (int j = 0; j < 4; ++j) {
        const int n = col0 + j * 16 + l15;
        const int h = n >> 6, d = n & 63;
#pragma unroll
        for (int r = 0; r < 4; ++r) {
          const int m = row0 + i * 16 + l4 * 4 + r;
          const int b = m >> 11, s = m & 2047;
          out[(size_t)(b * NH + h) * (SEQ * DK) + s * DK + d] = f2bf(acc[i][j][r] * scale);
        }
      }
    }
  } else if constexpr (MODE == 1) {
    unsigned short* out = (unsigned short*)Cp;
#pragma unroll
    for (int i = 0; i < 4; ++i) {
      const int m0 = row0 + i * 16 + l4 * 4;
      const int b = m0 >> 11, s0 = m0 & 2047;
#pragma unroll
      for (int j = 0; j < 4; ++j) {
        const int n = col0 + j * 16 + l15;
        const int h = n >> 6, d = n & 63;
        us4 pk;
        pk.x = f2bf(acc[i][j][0]);
        pk.y = f2bf(acc[i][j][1]);
        pk.z = f2bf(acc[i][j][2]);
        pk.w = f2bf(acc[i][j][3]);
        *reinterpret_cast<us4*>(&out[(size_t)(b * NH + h) * (DK * SEQ) + d * SEQ + s0]) = pk;
      }
    }
  } else {
    float* out = (float*)Cp;
#pragma unroll
    for (int i = 0; i < 4; ++i)
#pragma unroll
      for (int j = 0; j < 4; ++j)
#pragma unroll
        for (int r = 0; r < 4; ++r) {
          const int m = row0 + i * 16 + l4 * 4 + r;
          const int n = col0 + j * 16 + l15;
          out[(size_t)m * DMODEL + n] = acc[i][j][r];
        }
  }
}

// ---------------- causal flash attention v3 ----------------
// 8 waves/block, 16 q-rows/wave (swapped-QK^T in-register softmax).
// Block x handles q-tiles {15-x, x} (128 rows each) => uniform 34 k-tiles/block.
// K/V tiles (64x64 bf16 each) staged in LDS, double-buffered, via
// global_load_lds with pre-swizzled global source (granule XOR row&7).
__global__ __launch_bounds__(512, 2) void attn_kernel(const unsigned short* __restrict__ Qh,
                                                      const unsigned short* __restrict__ Kh,
                                                      const unsigned short* __restrict__ Vt,
                                                      unsigned short* __restrict__ Mg) {
  __shared__ __align__(16) unsigned short Kl[2][64 * 64];
  __shared__ __align__(16) unsigned short Vl[2][64 * 64];

  const int tid = threadIdx.x;
  const int lane = tid & 63;
  const int w = tid >> 6;
  const int l15 = lane & 15, l4 = lane >> 4;
  const int xp = blockIdx.x;  // 0..7
  const int bh = blockIdx.y;

  const unsigned short* Qb = Qh + (size_t)bh * SEQ * DK;
  const unsigned short* Kb = Kh + (size_t)bh * SEQ * DK;
  const unsigned short* Vb = Vt + (size_t)bh * DK * SEQ;
  const int bq = bh >> 4, hh = bh & 15;
  unsigned short* Mbase = Mg + (size_t)bq * SEQ * DMODEL + hh * DK;

  // staging lane constants: lane covers row (w*8 + lane/8), swizzled granule
  const int srow = lane >> 3;                 // 0..7
  const int sswz = (lane & 7) ^ srow;         // source granule (involution)
  const unsigned short* KsrcB = Kb + (size_t)(w * 8 + srow) * DK + sswz * 8;
  const unsigned short* VsrcB = Vb + (size_t)(w * 8 + srow) * SEQ + sswz * 8;

  const int l7 = l15 & 7;  // row&7 for all fragment reads below

  const int qtiles[2] = {15 - xp, xp};

#pragma unroll 1
  for (int seg = 0; seg < 2; ++seg) {
    const int qbase = qtiles[seg] * 128;
    const int q0w = qbase + w * 16;           // wave's first q row
    const int nt = (qbase >> 6) + 2;

    bf16x8 qf0 = *reinterpret_cast<const bf16x8*>(Qb + (size_t)(q0w + l15) * DK + l4 * 8);
    bf16x8 qf1 = *reinterpret_cast<const bf16x8*>(Qb + (size_t)(q0w + l15) * DK + 32 + l4 * 8);

    f32x4 o[4] = {};
    float mrow = -__builtin_inff();
    float lrow = 0.0f;

    // prologue: stage tile 0 into buf 0
    gload16(KsrcB, &Kl[0][w * 512]);
    gload16(VsrcB, &Vl[0][w * 512]);

#pragma unroll 1
    for (int t = 0; t < nt; ++t) {
      const int kbase = t << 6;
      const int cur = t & 1;
      const bool haveNext = (t + 1 < nt);
      if (haveNext) {
        unsigned short* kd = (cur ? &Kl[0][w * 512] : &Kl[1][w * 512]);
        unsigned short* vd = (cur ? &Vl[0][w * 512] : &Vl[1][w * 512]);
        gload16(KsrcB + (size_t)(kbase + 64) * DK, kd);
        gload16(VsrcB + (kbase + 64), vd);
        asm volatile("s_waitcnt vmcnt(2)" ::: "memory");
      } else {
        asm volatile("s_waitcnt vmcnt(0)" ::: "memory");
      }
      __builtin_amdgcn_sched_barrier(0);
      __builtin_amdgcn_s_barrier();
      __builtin_amdgcn_sched_barrier(0);

      if (kbase < q0w + 16) {  // wave-uniform: skip fully-masked tiles
        const unsigned short* Kc = cur ? Kl[1] : Kl[0];
        const unsigned short* Vc = cur ? Vl[1] : Vl[0];

        // ---- S^T = K Q^T ----
        f32x4 sc[4];
#pragma unroll
        for (int c = 0; c < 4; ++c) {
          const int krow = c * 16 + l15;
          bf16x8 kf0 = *reinterpret_cast<const bf16x8*>(&Kc[krow * 64 + ((l4 ^ l7) * 8)]);
          bf16x8 kf1 = *reinterpret_cast<const bf16x8*>(&Kc[krow * 64 + (((4 + l4) ^ l7) * 8)]);
          f32x4 z = {0.f, 0.f, 0.f, 0.f};
          z = mfma_bf16(kf0, qf0, z);
          sc[c] = mfma_bf16(kf1, qf1, z);
        }

        // ---- causal mask (diagonal tiles only) ----
        if (kbase + 63 > q0w) {
          const int qg = q0w + l15;
#pragma unroll
          for (int c = 0; c < 4; ++c) {
            const int kp = kbase + c * 16 + l4 * 4;
#pragma unroll
            for (int r = 0; r < 4; ++r)
              if (kp + r > qg) sc[c][r] = -__builtin_inff();
          }
        }

        // ---- online softmax (in-lane + shfl over l4 groups) ----
        f32x4 mv = sc[0];
#pragma unroll
        for (int c = 1; c < 4; ++c)
#pragma unroll
          for (int r = 0; r < 4; ++r) mv[r] = fmaxf(mv[r], sc[c][r]);
        float pm = fmaxf(fmaxf(mv[0], mv[1]), fmaxf(mv[2], mv[3]));
        pm = fmaxf(pm, __shfl_xor(pm, 16));
        pm = fmaxf(pm, __shfl_xor(pm, 32));
        const float mn = fmaxf(mrow, pm);
        const float al = __builtin_amdgcn_exp2f(mrow - mn);
        mrow = mn;
        f32x4 sv = {0.f, 0.f, 0.f, 0.f};
        us4 pb[4];
#pragma unroll
        for (int c = 0; c < 4; ++c) {
#pragma unroll
          for (int r = 0; r < 4; ++r) {
            const float p = __builtin_amdgcn_exp2f(sc[c][r] - mn);
            sc[c][r] = p;
            sv[r] += p;
          }
          us4 pk;
          pk.x = f2bf(sc[c][0]);
          pk.y = f2bf(sc[c][1]);
          pk.z = f2bf(sc[c][2]);
          pk.w = f2bf(sc[c][3]);
          pb[c] = pk;
        }
        float rs = (sv[0] + sv[1]) + (sv[2] + sv[3]);
        rs += __shfl_xor(rs, 16);
        rs += __shfl_xor(rs, 32);
        lrow = lrow * al + rs;
#pragma unroll
        for (int dd = 0; dd < 4; ++dd)
#pragma unroll
          for (int r = 0; r < 4; ++r) o[dd][r] *= al;

        // ---- O^T += V^T P ----
#pragma unroll
        for (int dd = 0; dd < 4; ++dd) {
          const int vrow = dd * 16 + l15;
#pragma unroll
          for (int c = 0; c < 4; ++c) {
            const us4 va = *reinterpret_cast<const us4*>(
                &Vc[vrow * 64 + (((c * 2 + (l4 >> 1)) ^ l7) * 8) + (l4 & 1) * 4]);
            o[dd] = mfma_k16(va, pb[c], o[dd]);
          }
        }
      }

      __builtin_amdgcn_sched_barrier(0);
      __builtin_amdgcn_s_barrier();
      __builtin_amdgcn_sched_barrier(0);
    }

    // ---- epilogue ----
    const float inv = __builtin_amdgcn_rcpf(lrow);
    const int s = q0w + l15;
#pragma unroll
    for (int dd = 0; dd < 4; ++dd) {
      us4 pk;
      pk.x = f2bf(o[dd][0] * inv);
      pk.y = f2bf(o[dd][1] * inv);
      pk.z = f2bf(o[dd][2] * inv);
      pk.w = f2bf(o[dd][3] * inv);
      *reinterpret_cast<us4*>(&Mbase[(size_t)s * DMODEL + dd * 16 + l4 * 4]) = pk;
    }
  }
}

extern "C" void kernel_launch(void* const* d_in, const int* in_sizes, int n_in,
                              void* d_out, int out_size, void* d_ws, size_t ws_size,
                              hipStream_t stream) {
  (void)in_sizes; (void)n_in; (void)out_size;
  if (ws_size < (size_t)64 * (1 << 20)) return;  // need 64MB scratch

  const float* q = (const float*)d_in[0];
  const float* k = (const float*)d_in[1];
  const float* v = (const float*)d_in[2];
  // d_in[3] = mask (causal, hardcoded)
  const float* wq = (const float*)d_in[4];
  const float* wk = (const float*)d_in[5];
  const float* wv = (const float*)d_in[6];
  const float* wo = (const float*)d_in[7];

  char* ws = (char*)d_ws;
  unsigned short* xq  = (unsigned short*)(ws + (size_t)0  * (1 << 20));
  unsigned short* xk  = (unsigned short*)(ws + (size_t)8  * (1 << 20));
  unsigned short* xv  = (unsigned short*)(ws + (size_t)16 * (1 << 20));
  unsigned short* bwq = (unsigned short*)(ws + (size_t)24 * (1 << 20));
  unsigned short* bwk = (unsigned short*)(ws + (size_t)26 * (1 << 20));
  unsigned short* bwv = (unsigned short*)(ws + (size_t)28 * (1 << 20));
  unsigned short* bwo = (unsigned short*)(ws + (size_t)30 * (1 << 20));
  unsigned short* Qh  = (unsigned short*)(ws + (size_t)32 * (1 << 20));
  unsigned short* Kh  = (unsigned short*)(ws + (size_t)40 * (1 << 20));
  unsigned short* Vt  = (unsigned short*)(ws + (size_t)48 * (1 << 20));
  unsigned short* Mg  = (unsigned short*)(ws + (size_t)56 * (1 << 20));

  cvt3_kernel<<<dim3(512, 3), 256, 0, stream>>>(q, k, v, xq, xk, xv, (MTOT * DMODEL) / 4);
  cvt4_kernel<<<dim3(256, 4), 256, 0, stream>>>(wq, wk, wv, wo, bwq, bwk, bwv, bwo,
                                                (DMODEL * DMODEL) / 4);
  dim3 gg(32, 8);
  // Q pre-scaled by (1/sqrt(64)) * log2(e) so softmax uses exp2 directly
  gemm_bt<0><<<gg, 256, 0, stream>>>(xq, bwq, Qh, 0.18033688011112042f);
  gemm_bt<0><<<gg, 256, 0, stream>>>(xk, bwk, Kh, 1.0f);
  gemm_bt<1><<<gg, 256, 0, stream>>>(xv, bwv, Vt, 1.0f);
  attn_kernel<<<dim3(8, 32), 512, 0, stream>>>(Qh, Kh, Vt, Mg);
  gemm_bt<2><<<gg, 256, 0, stream>>>(Mg, bwo, d_out, 1.0f);
}

// Round 4
// 157.147 us; speedup vs baseline: 2.1521x; 1.0664x over previous
//
#include <hip/hip_runtime.h>
#include <hip/hip_bf16.h>
#include <stdint.h>

typedef __attribute__((ext_vector_type(4))) float f32x4;
typedef __attribute__((ext_vector_type(8))) __bf16 bf16x8;
typedef __attribute__((ext_vector_type(4))) unsigned short us4;
typedef __attribute__((ext_vector_type(4))) short v4ss;

#define SEQ 2048
#define DMODEL 1024
#define NH 16
#define DK 64
#define MTOT 4096  // B*SEQ

__device__ __forceinline__ unsigned short f2bf(float x) {
  union { float f; unsigned int u; } v; v.f = x;
  unsigned int r = v.u + 0x7fffu + ((v.u >> 16) & 1u);
  return (unsigned short)(r >> 16);
}

__device__ __forceinline__ f32x4 mfma_bf16(bf16x8 a, bf16x8 b, f32x4 c) {
  return __builtin_amdgcn_mfma_f32_16x16x32_bf16(a, b, c, 0, 0, 0);
}

// K=16 MFMA: D[m][n] += sum_{k=0..15} A[m][k]*B[n][k]
// lane holds row m|n = lane&15, k = (lane>>4)*4 + j (j=0..3)
__device__ __forceinline__ f32x4 mfma_k16(us4 a, us4 b, f32x4 c) {
#if __has_builtin(__builtin_amdgcn_mfma_f32_16x16x16bf16_1k)
  return __builtin_amdgcn_mfma_f32_16x16x16bf16_1k(
      __builtin_bit_cast(v4ss, a), __builtin_bit_cast(v4ss, b), c, 0, 0, 0);
#else
  // exact emulation on K=32: zeros in upper half contribute 0
  union U { bf16x8 v; us4 h[2]; } ua, ub;
  us4 z = {0, 0, 0, 0};
  ua.h[0] = a; ua.h[1] = z;
  ub.h[0] = b; ub.h[1] = z;
  return mfma_bf16(ua.v, ub.v, c);
#endif
}

__device__ __forceinline__ void gload16(const unsigned short* g, unsigned short* l) {
  __builtin_amdgcn_global_load_lds((__attribute__((address_space(1))) void*)g,
                                   (__attribute__((address_space(3))) void*)l,
                                   16, 0, 0);
}

// ---------------- fp32 -> bf16 conversion (all 7 tensors, one launch) ----------------
__global__ void cvt_all(const float* __restrict__ s0, const float* __restrict__ s1,
                        const float* __restrict__ s2, const float* __restrict__ s3,
                        const float* __restrict__ s4, const float* __restrict__ s5,
                        const float* __restrict__ s6,
                        unsigned short* __restrict__ d0, unsigned short* __restrict__ d1,
                        unsigned short* __restrict__ d2, unsigned short* __restrict__ d3,
                        unsigned short* __restrict__ d4, unsigned short* __restrict__ d5,
                        unsigned short* __restrict__ d6) {
  const int y = blockIdx.y;
  const float* s = y == 0 ? s0 : y == 1 ? s1 : y == 2 ? s2 : y == 3 ? s3
                 : y == 4 ? s4 : y == 5 ? s5 : s6;
  unsigned short* d = y == 0 ? d0 : y == 1 ? d1 : y == 2 ? d2 : y == 3 ? d3
                    : y == 4 ? d4 : y == 5 ? d5 : d6;
  const int n4 = (y < 3) ? (MTOT * DMODEL / 4) : (DMODEL * DMODEL / 4);
  const int stride = gridDim.x * blockDim.x;
  for (int i = blockIdx.x * blockDim.x + threadIdx.x; i < n4; i += stride) {
    f32x4 v = reinterpret_cast<const f32x4*>(s)[i];
    us4 o;
    o.x = f2bf(v.x); o.y = f2bf(v.y); o.z = f2bf(v.z); o.w = f2bf(v.w);
    reinterpret_cast<us4*>(d)[i] = o;
  }
}

// ---------------- fused QKV GEMM: C[m,n] = sum_k A[m,k]*B[n,k], K=1024 ----------------
// z=0: Q (head layout, scaled), z=1: K (head layout), z=2: V (V^T layout)
__global__ __launch_bounds__(256) void gemm_qkv(
    const unsigned short* __restrict__ xq, const unsigned short* __restrict__ xk,
    const unsigned short* __restrict__ xv, const unsigned short* __restrict__ bwq,
    const unsigned short* __restrict__ bwk, const unsigned short* __restrict__ bwv,
    unsigned short* __restrict__ Qh, unsigned short* __restrict__ Kh,
    unsigned short* __restrict__ Vt) {
  const int z = blockIdx.z;
  const unsigned short* A = z == 0 ? xq : (z == 1 ? xk : xv);
  const unsigned short* B = z == 0 ? bwq : (z == 1 ? bwk : bwv);
  unsigned short* out = z == 0 ? Qh : (z == 1 ? Kh : Vt);
  const float scale = z == 0 ? 0.18033688011112042f : 1.0f;  // (1/8)*log2(e) for Q

  __shared__ __align__(16) unsigned short lA[128 * 32];
  __shared__ __align__(16) unsigned short lB[128 * 32];
  const int tid = threadIdx.x;
  const int lane = tid & 63;
  const int wid = tid >> 6;
  const int l15 = lane & 15, l4 = lane >> 4;
  const int bm = blockIdx.x, bn = blockIdx.y;
  const int wr = wid >> 1, wc = wid & 1;

  f32x4 acc[4][4] = {};

  const int chunk0 = (wid * 2 + 0) * 64 + lane;
  const int chunk1 = (wid * 2 + 1) * 64 + lane;
  const unsigned short* gA0 = A + (size_t)(bm * 128 + (chunk0 >> 2)) * 1024 + (chunk0 & 3) * 8;
  const unsigned short* gA1 = A + (size_t)(bm * 128 + (chunk1 >> 2)) * 1024 + (chunk1 & 3) * 8;
  const unsigned short* gB0 = B + (size_t)(bn * 128 + (chunk0 >> 2)) * 1024 + (chunk0 & 3) * 8;
  const unsigned short* gB1 = B + (size_t)(bn * 128 + (chunk1 >> 2)) * 1024 + (chunk1 & 3) * 8;
  unsigned short* lA0 = lA + (wid * 2 + 0) * 512;
  unsigned short* lA1 = lA + (wid * 2 + 1) * 512;
  unsigned short* lB0 = lB + (wid * 2 + 0) * 512;
  unsigned short* lB1 = lB + (wid * 2 + 1) * 512;

  for (int kt = 0; kt < 1024; kt += 32) {
    __syncthreads();
    gload16(gA0 + kt, lA0);
    gload16(gA1 + kt, lA1);
    gload16(gB0 + kt, lB0);
    gload16(gB1 + kt, lB1);
    __syncthreads();
    bf16x8 af[4], bfr[4];
#pragma unroll
    for (int i = 0; i < 4; ++i)
      af[i] = *reinterpret_cast<const bf16x8*>(&lA[(wr * 64 + i * 16 + l15) * 32 + l4 * 8]);
#pragma unroll
    for (int j = 0; j < 4; ++j)
      bfr[j] = *reinterpret_cast<const bf16x8*>(&lB[(wc * 64 + j * 16 + l15) * 32 + l4 * 8]);
#pragma unroll
    for (int i = 0; i < 4; ++i)
#pragma unroll
      for (int j = 0; j < 4; ++j)
        acc[i][j] = mfma_bf16(af[i], bfr[j], acc[i][j]);
  }

  const int row0 = bm * 128 + wr * 64;
  const int col0 = bn * 128 + wc * 64;

  if (z < 2) {
#pragma unroll
    for (int i = 0; i < 4; ++i) {
#pragma unroll
      for (int j = 0; j < 4; ++j) {
        const int n = col0 + j * 16 + l15;
        const int h = n >> 6, dd = n & 63;
#pragma unroll
        for (int r = 0; r < 4; ++r) {
          const int m = row0 + i * 16 + l4 * 4 + r;
          const int b = m >> 11, s = m & 2047;
          out[(size_t)(b * NH + h) * (SEQ * DK) + s * DK + dd] = f2bf(acc[i][j][r] * scale);
        }
      }
    }
  } else {
#pragma unroll
    for (int i = 0; i < 4; ++i) {
      const int m0 = row0 + i * 16 + l4 * 4;
      const int b = m0 >> 11, s0 = m0 & 2047;
#pragma unroll
      for (int j = 0; j < 4; ++j) {
        const int n = col0 + j * 16 + l15;
        const int h = n >> 6, dd = n & 63;
        us4 pk;
        pk.x = f2bf(acc[i][j][0]);
        pk.y = f2bf(acc[i][j][1]);
        pk.z = f2bf(acc[i][j][2]);
        pk.w = f2bf(acc[i][j][3]);
        *reinterpret_cast<us4*>(&out[(size_t)(b * NH + h) * (DK * SEQ) + dd * SEQ + s0]) = pk;
      }
    }
  }
}

// ---------------- output-projection GEMM (f32 out) ----------------
__global__ __launch_bounds__(256) void gemm_o(const unsigned short* __restrict__ A,
                                              const unsigned short* __restrict__ B,
                                              float* __restrict__ out) {
  __shared__ __align__(16) unsigned short lA[128 * 32];
  __shared__ __align__(16) unsigned short lB[128 * 32];
  const int tid = threadIdx.x;
  const int lane = tid & 63;
  const int wid = tid >> 6;
  const int l15 = lane & 15, l4 = lane >> 4;
  const int bm = blockIdx.x, bn = blockIdx.y;
  const int wr = wid >> 1, wc = wid & 1;

  f32x4 acc[4][4] = {};

  const int chunk0 = (wid * 2 + 0) * 64 + lane;
  const int chunk1 = (wid * 2 + 1) * 64 + lane;
  const unsigned short* gA0 = A + (size_t)(bm * 128 + (chunk0 >> 2)) * 1024 + (chunk0 & 3) * 8;
  const unsigned short* gA1 = A + (size_t)(bm * 128 + (chunk1 >> 2)) * 1024 + (chunk1 & 3) * 8;
  const unsigned short* gB0 = B + (size_t)(bn * 128 + (chunk0 >> 2)) * 1024 + (chunk0 & 3) * 8;
  const unsigned short* gB1 = B + (size_t)(bn * 128 + (chunk1 >> 2)) * 1024 + (chunk1 & 3) * 8;
  unsigned short* lA0 = lA + (wid * 2 + 0) * 512;
  unsigned short* lA1 = lA + (wid * 2 + 1) * 512;
  unsigned short* lB0 = lB + (wid * 2 + 0) * 512;
  unsigned short* lB1 = lB + (wid * 2 + 1) * 512;

  for (int kt = 0; kt < 1024; kt += 32) {
    __syncthreads();
    gload16(gA0 + kt, lA0);
    gload16(gA1 + kt, lA1);
    gload16(gB0 + kt, lB0);
    gload16(gB1 + kt, lB1);
    __syncthreads();
    bf16x8 af[4], bfr[4];
#pragma unroll
    for (int i = 0; i < 4; ++i)
      af[i] = *reinterpret_cast<const bf16x8*>(&lA[(wr * 64 + i * 16 + l15) * 32 + l4 * 8]);
#pragma unroll
    for (int j = 0; j < 4; ++j)
      bfr[j] = *reinterpret_cast<const bf16x8*>(&lB[(wc * 64 + j * 16 + l15) * 32 + l4 * 8]);
#pragma unroll
    for (int i = 0; i < 4; ++i)
#pragma unroll
      for (int j = 0; j < 4; ++j)
        acc[i][j] = mfma_bf16(af[i], bfr[j], acc[i][j]);
  }

  const int row0 = bm * 128 + wr * 64;
  const int col0 = bn * 128 + wc * 64;
#pragma unroll
  for (int i = 0; i < 4; ++i)
#pragma unroll
    for (int j = 0; j < 4; ++j)
#pragma unroll
      for (int r = 0; r < 4; ++r) {
        const int m = row0 + i * 16 + l4 * 4 + r;
        const int n = col0 + j * 16 + l15;
        out[(size_t)m * DMODEL + n] = acc[i][j][r];
      }
}

// ---------------- causal flash attention v4 ----------------
// 512 blocks x 8 waves; one 128-row q-tile per block. XCD-affinity decode:
// all 16 blocks of a (b,h) land on XCD bh&7, long tiles dispatched first.
// K/V 64x64 tiles staged in LDS via global_load_lds (pre-swizzled source),
// TRIPLE-buffered with distance-2 prefetch and counted vmcnt.
__global__ __launch_bounds__(512, 4) void attn_kernel(const unsigned short* __restrict__ Qh,
                                                      const unsigned short* __restrict__ Kh,
                                                      const unsigned short* __restrict__ Vt,
                                                      unsigned short* __restrict__ Mg) {
  __shared__ __align__(16) unsigned short Kl[3][64 * 64];
  __shared__ __align__(16) unsigned short Vl[3][64 * 64];

  const int tid = threadIdx.x;
  const int lane = tid & 63;
  const int w = tid >> 6;
  const int l15 = lane & 15, l4 = lane >> 4;

  // XCD-affinity decode: dispatch d -> XCD d&7 (round-robin assumption, perf-only)
  const int d = blockIdx.x;
  const int xcd = d & 7;
  const int j = d >> 3;             // 0..63
  const int bh = (j >> 4) * 8 + xcd;
  const int tau = 15 - (j & 15);    // long q-tiles first in dispatch order

  const unsigned short* Qb = Qh + (size_t)bh * SEQ * DK;
  const unsigned short* Kb = Kh + (size_t)bh * SEQ * DK;
  const unsigned short* Vb = Vt + (size_t)bh * DK * SEQ;
  const int bq = bh >> 4, hh = bh & 15;
  unsigned short* Mbase = Mg + (size_t)bq * SEQ * DMODEL + hh * DK;

  // staging lane constants: lane covers row (w*8 + lane/8), swizzled granule
  const int srow = lane >> 3;              // 0..7
  const int sswz = (lane & 7) ^ srow;      // source granule (involution)
  const unsigned short* KsrcB = Kb + (size_t)(w * 8 + srow) * DK + sswz * 8;
  const unsigned short* VsrcB = Vb + (size_t)(w * 8 + srow) * SEQ + sswz * 8;

  const int l7 = l15 & 7;

  const int qbase = tau * 128;
  const int q0w = qbase + w * 16;
  const int nt = 2 * tau + 2;

  bf16x8 qf0 = *reinterpret_cast<const bf16x8*>(Qb + (size_t)(q0w + l15) * DK + l4 * 8);
  bf16x8 qf1 = *reinterpret_cast<const bf16x8*>(Qb + (size_t)(q0w + l15) * DK + 32 + l4 * 8);

  f32x4 o[4] = {};
  float mrow = -__builtin_inff();
  float lrow = 0.0f;

  // prologue: stage tiles 0,1 into bufs 0,1
  gload16(KsrcB, &Kl[0][w * 512]);
  gload16(VsrcB, &Vl[0][w * 512]);
  gload16(KsrcB + (size_t)64 * DK, &Kl[1][w * 512]);
  gload16(VsrcB + 64, &Vl[1][w * 512]);

  int bi = 0;  // buffer holding tile t
#pragma unroll 1
  for (int t = 0; t < nt; ++t) {
    const int kbase = t << 6;
    if (t + 1 < nt) {
      asm volatile("s_waitcnt vmcnt(2)" ::: "memory");
    } else {
      asm volatile("s_waitcnt vmcnt(0)" ::: "memory");
    }
    __builtin_amdgcn_sched_barrier(0);
    __builtin_amdgcn_s_barrier();
    __builtin_amdgcn_sched_barrier(0);

    // stage tile t+2 into buffer (t+2)%3 == (t-1)%3 (its readers are done: barrier)
    if (t + 2 < nt) {
      const int pb = (bi == 0) ? 2 : bi - 1;
      gload16(KsrcB + (size_t)(kbase + 128) * DK, &Kl[pb][w * 512]);
      gload16(VsrcB + (kbase + 128), &Vl[pb][w * 512]);
    }

    if (kbase < q0w + 16) {  // wave-uniform causal skip
      const unsigned short* Kc = Kl[bi];
      const unsigned short* Vc = Vl[bi];

      // ---- S^T = K Q^T ----
      f32x4 sc[4];
#pragma unroll
      for (int c = 0; c < 4; ++c) {
        const int krow = c * 16 + l15;
        bf16x8 kf0 = *reinterpret_cast<const bf16x8*>(&Kc[krow * 64 + ((l4 ^ l7) * 8)]);
        bf16x8 kf1 = *reinterpret_cast<const bf16x8*>(&Kc[krow * 64 + (((4 + l4) ^ l7) * 8)]);
        f32x4 z = {0.f, 0.f, 0.f, 0.f};
        z = mfma_bf16(kf0, qf0, z);
        sc[c] = mfma_bf16(kf1, qf1, z);
      }

      // ---- causal mask (diagonal tiles only) ----
      if (kbase + 63 > q0w) {
        const int qg = q0w + l15;
#pragma unroll
        for (int c = 0; c < 4; ++c) {
          const int kp = kbase + c * 16 + l4 * 4;
#pragma unroll
          for (int r = 0; r < 4; ++r)
            if (kp + r > qg) sc[c][r] = -__builtin_inff();
        }
      }

      // ---- online softmax ----
      f32x4 mv = sc[0];
#pragma unroll
      for (int c = 1; c < 4; ++c)
#pragma unroll
        for (int r = 0; r < 4; ++r) mv[r] = fmaxf(mv[r], sc[c][r]);
      float pm = fmaxf(fmaxf(mv[0], mv[1]), fmaxf(mv[2], mv[3]));
      pm = fmaxf(pm, __shfl_xor(pm, 16));
      pm = fmaxf(pm, __shfl_xor(pm, 32));
      const float mn = fmaxf(mrow, pm);
      const float al = __builtin_amdgcn_exp2f(mrow - mn);
      mrow = mn;
      f32x4 sv = {0.f, 0.f, 0.f, 0.f};
      us4 pb4[4];
#pragma unroll
      for (int c = 0; c < 4; ++c) {
#pragma unroll
        for (int r = 0; r < 4; ++r) {
          const float p = __builtin_amdgcn_exp2f(sc[c][r] - mn);
          sc[c][r] = p;
          sv[r] += p;
        }
        us4 pk;
        pk.x = f2bf(sc[c][0]);
        pk.y = f2bf(sc[c][1]);
        pk.z = f2bf(sc[c][2]);
        pk.w = f2bf(sc[c][3]);
        pb4[c] = pk;
      }
      float rs = (sv[0] + sv[1]) + (sv[2] + sv[3]);
      rs += __shfl_xor(rs, 16);
      rs += __shfl_xor(rs, 32);
      lrow = lrow * al + rs;
#pragma unroll
      for (int dd = 0; dd < 4; ++dd)
#pragma unroll
        for (int r = 0; r < 4; ++r) o[dd][r] *= al;

      // ---- O^T += V^T P ----
#pragma unroll
      for (int dd = 0; dd < 4; ++dd) {
        const int vrow = dd * 16 + l15;
#pragma unroll
        for (int c = 0; c < 4; ++c) {
          const us4 va = *reinterpret_cast<const us4*>(
              &Vc[vrow * 64 + (((c * 2 + (l4 >> 1)) ^ l7) * 8) + (l4 & 1) * 4]);
          o[dd] = mfma_k16(va, pb4[c], o[dd]);
        }
      }
    }

    bi = (bi == 2) ? 0 : bi + 1;
  }

  // ---- epilogue ----
  const float inv = __builtin_amdgcn_rcpf(lrow);
  const int s = q0w + l15;
#pragma unroll
  for (int dd = 0; dd < 4; ++dd) {
    us4 pk;
    pk.x = f2bf(o[dd][0] * inv);
    pk.y = f2bf(o[dd][1] * inv);
    pk.z = f2bf(o[dd][2] * inv);
    pk.w = f2bf(o[dd][3] * inv);
    *reinterpret_cast<us4*>(&Mbase[(size_t)s * DMODEL + dd * 16 + l4 * 4]) = pk;
  }
}

extern "C" void kernel_launch(void* const* d_in, const int* in_sizes, int n_in,
                              void* d_out, int out_size, void* d_ws, size_t ws_size,
                              hipStream_t stream) {
  (void)in_sizes; (void)n_in; (void)out_size;
  if (ws_size < (size_t)64 * (1 << 20)) return;  // need 64MB scratch

  const float* q = (const float*)d_in[0];
  const float* k = (const float*)d_in[1];
  const float* v = (const float*)d_in[2];
  // d_in[3] = mask (causal, hardcoded)
  const float* wq = (const float*)d_in[4];
  const float* wk = (const float*)d_in[5];
  const float* wv = (const float*)d_in[6];
  const float* wo = (const float*)d_in[7];

  char* ws = (char*)d_ws;
  unsigned short* xq  = (unsigned short*)(ws + (size_t)0  * (1 << 20));
  unsigned short* xk  = (unsigned short*)(ws + (size_t)8  * (1 << 20));
  unsigned short* xv  = (unsigned short*)(ws + (size_t)16 * (1 << 20));
  unsigned short* bwq = (unsigned short*)(ws + (size_t)24 * (1 << 20));
  unsigned short* bwk = (unsigned short*)(ws + (size_t)26 * (1 << 20));
  unsigned short* bwv = (unsigned short*)(ws + (size_t)28 * (1 << 20));
  unsigned short* bwo = (unsigned short*)(ws + (size_t)30 * (1 << 20));
  unsigned short* Qh  = (unsigned short*)(ws + (size_t)32 * (1 << 20));
  unsigned short* Kh  = (unsigned short*)(ws + (size_t)40 * (1 << 20));
  unsigned short* Vt  = (unsigned short*)(ws + (size_t)48 * (1 << 20));
  unsigned short* Mg  = (unsigned short*)(ws + (size_t)56 * (1 << 20));

  cvt_all<<<dim3(256, 7), 256, 0, stream>>>(q, k, v, wq, wk, wv, wo,
                                            xq, xk, xv, bwq, bwk, bwv, bwo);
  gemm_qkv<<<dim3(32, 8, 3), 256, 0, stream>>>(xq, xk, xv, bwq, bwk, bwv, Qh, Kh, Vt);
  attn_kernel<<<dim3(512), 512, 0, stream>>>(Qh, Kh, Vt, Mg);
  gemm_o<<<dim3(32, 8), 256, 0, stream>>>(Mg, bwo, (float*)d_out);
}

// Round 5
// 145.203 us; speedup vs baseline: 2.3292x; 1.0823x over previous
//
#include <hip/hip_runtime.h>
#include <hip/hip_bf16.h>
#include <stdint.h>

typedef __attribute__((ext_vector_type(4))) float f32x4;
typedef __attribute__((ext_vector_type(8))) __bf16 bf16x8;
typedef __attribute__((ext_vector_type(4))) unsigned short us4;
typedef __attribute__((ext_vector_type(4))) short v4ss;

#define SEQ 2048
#define DMODEL 1024
#define NH 16
#define DK 64
#define MTOT 4096  // B*SEQ

__device__ __forceinline__ unsigned short f2bf(float x) {
  union { float f; unsigned int u; } v; v.f = x;
  unsigned int r = v.u + 0x7fffu + ((v.u >> 16) & 1u);
  return (unsigned short)(r >> 16);
}

__device__ __forceinline__ f32x4 mfma_bf16(bf16x8 a, bf16x8 b, f32x4 c) {
  return __builtin_amdgcn_mfma_f32_16x16x32_bf16(a, b, c, 0, 0, 0);
}

// K=16 MFMA: D[m][n] += sum_{k=0..15} A[m][k]*B[n][k]
// lane holds row m|n = lane&15, k = (lane>>4)*4 + j (j=0..3)
__device__ __forceinline__ f32x4 mfma_k16(us4 a, us4 b, f32x4 c) {
#if __has_builtin(__builtin_amdgcn_mfma_f32_16x16x16bf16_1k)
  return __builtin_amdgcn_mfma_f32_16x16x16bf16_1k(
      __builtin_bit_cast(v4ss, a), __builtin_bit_cast(v4ss, b), c, 0, 0, 0);
#else
  // exact emulation on K=32: zeros in upper half contribute 0
  union U { bf16x8 v; us4 h[2]; } ua, ub;
  us4 z = {0, 0, 0, 0};
  ua.h[0] = a; ua.h[1] = z;
  ub.h[0] = b; ub.h[1] = z;
  return mfma_bf16(ua.v, ub.v, c);
#endif
}

__device__ __forceinline__ void gload16(const unsigned short* g, unsigned short* l) {
  __builtin_amdgcn_global_load_lds((__attribute__((address_space(1))) void*)g,
                                   (__attribute__((address_space(3))) void*)l,
                                   16, 0, 0);
}

// ---------------- fp32 -> bf16 conversion (all 7 tensors, one launch) ----------------
__global__ void cvt_all(const float* __restrict__ s0, const float* __restrict__ s1,
                        const float* __restrict__ s2, const float* __restrict__ s3,
                        const float* __restrict__ s4, const float* __restrict__ s5,
                        const float* __restrict__ s6,
                        unsigned short* __restrict__ d0, unsigned short* __restrict__ d1,
                        unsigned short* __restrict__ d2, unsigned short* __restrict__ d3,
                        unsigned short* __restrict__ d4, unsigned short* __restrict__ d5,
                        unsigned short* __restrict__ d6) {
  const int y = blockIdx.y;
  const float* s = y == 0 ? s0 : y == 1 ? s1 : y == 2 ? s2 : y == 3 ? s3
                 : y == 4 ? s4 : y == 5 ? s5 : s6;
  unsigned short* d = y == 0 ? d0 : y == 1 ? d1 : y == 2 ? d2 : y == 3 ? d3
                    : y == 4 ? d4 : y == 5 ? d5 : d6;
  const int n4 = (y < 3) ? (MTOT * DMODEL / 4) : (DMODEL * DMODEL / 4);
  const int stride = gridDim.x * blockDim.x;
  for (int i = blockIdx.x * blockDim.x + threadIdx.x; i < n4; i += stride) {
    f32x4 v = reinterpret_cast<const f32x4*>(s)[i];
    us4 o;
    o.x = f2bf(v.x); o.y = f2bf(v.y); o.z = f2bf(v.z); o.w = f2bf(v.w);
    reinterpret_cast<us4*>(d)[i] = o;
  }
}

// ---------------- fused QKV GEMM: C[m,n] = sum_k A[m,k]*B[n,k], K=1024 ----------------
// z=0: Q (head layout, scaled), z=1: K (head layout), z=2: V (V^T layout)
__global__ __launch_bounds__(256) void gemm_qkv(
    const unsigned short* __restrict__ xq, const unsigned short* __restrict__ xk,
    const unsigned short* __restrict__ xv, const unsigned short* __restrict__ bwq,
    const unsigned short* __restrict__ bwk, const unsigned short* __restrict__ bwv,
    unsigned short* __restrict__ Qh, unsigned short* __restrict__ Kh,
    unsigned short* __restrict__ Vt) {
  const int z = blockIdx.z;
  const unsigned short* A = z == 0 ? xq : (z == 1 ? xk : xv);
  const unsigned short* B = z == 0 ? bwq : (z == 1 ? bwk : bwv);
  unsigned short* out = z == 0 ? Qh : (z == 1 ? Kh : Vt);
  const float scale = z == 0 ? 0.18033688011112042f : 1.0f;  // (1/8)*log2(e) for Q

  __shared__ __align__(16) unsigned short lA[128 * 32];
  __shared__ __align__(16) unsigned short lB[128 * 32];
  const int tid = threadIdx.x;
  const int lane = tid & 63;
  const int wid = tid >> 6;
  const int l15 = lane & 15, l4 = lane >> 4;
  const int bm = blockIdx.x, bn = blockIdx.y;
  const int wr = wid >> 1, wc = wid & 1;

  f32x4 acc[4][4] = {};

  const int chunk0 = (wid * 2 + 0) * 64 + lane;
  const int chunk1 = (wid * 2 + 1) * 64 + lane;
  const unsigned short* gA0 = A + (size_t)(bm * 128 + (chunk0 >> 2)) * 1024 + (chunk0 & 3) * 8;
  const unsigned short* gA1 = A + (size_t)(bm * 128 + (chunk1 >> 2)) * 1024 + (chunk1 & 3) * 8;
  const unsigned short* gB0 = B + (size_t)(bn * 128 + (chunk0 >> 2)) * 1024 + (chunk0 & 3) * 8;
  const unsigned short* gB1 = B + (size_t)(bn * 128 + (chunk1 >> 2)) * 1024 + (chunk1 & 3) * 8;
  unsigned short* lA0 = lA + (wid * 2 + 0) * 512;
  unsigned short* lA1 = lA + (wid * 2 + 1) * 512;
  unsigned short* lB0 = lB + (wid * 2 + 0) * 512;
  unsigned short* lB1 = lB + (wid * 2 + 1) * 512;

  for (int kt = 0; kt < 1024; kt += 32) {
    __syncthreads();
    gload16(gA0 + kt, lA0);
    gload16(gA1 + kt, lA1);
    gload16(gB0 + kt, lB0);
    gload16(gB1 + kt, lB1);
    __syncthreads();
    bf16x8 af[4], bfr[4];
#pragma unroll
    for (int i = 0; i < 4; ++i)
      af[i] = *reinterpret_cast<const bf16x8*>(&lA[(wr * 64 + i * 16 + l15) * 32 + l4 * 8]);
#pragma unroll
    for (int j = 0; j < 4; ++j)
      bfr[j] = *reinterpret_cast<const bf16x8*>(&lB[(wc * 64 + j * 16 + l15) * 32 + l4 * 8]);
#pragma unroll
    for (int i = 0; i < 4; ++i)
#pragma unroll
      for (int j = 0; j < 4; ++j)
        acc[i][j] = mfma_bf16(af[i], bfr[j], acc[i][j]);
  }

  const int row0 = bm * 128 + wr * 64;
  const int col0 = bn * 128 + wc * 64;

  if (z < 2) {
#pragma unroll
    for (int i = 0; i < 4; ++i) {
#pragma unroll
      for (int j = 0; j < 4; ++j) {
        const int n = col0 + j * 16 + l15;
        const int h = n >> 6, dd = n & 63;
#pragma unroll
        for (int r = 0; r < 4; ++r) {
          const int m = row0 + i * 16 + l4 * 4 + r;
          const int b = m >> 11, s = m & 2047;
          out[(size_t)(b * NH + h) * (SEQ * DK) + s * DK + dd] = f2bf(acc[i][j][r] * scale);
        }
      }
    }
  } else {
#pragma unroll
    for (int i = 0; i < 4; ++i) {
      const int m0 = row0 + i * 16 + l4 * 4;
      const int b = m0 >> 11, s0 = m0 & 2047;
#pragma unroll
      for (int j = 0; j < 4; ++j) {
        const int n = col0 + j * 16 + l15;
        const int h = n >> 6, dd = n & 63;
        us4 pk;
        pk.x = f2bf(acc[i][j][0]);
        pk.y = f2bf(acc[i][j][1]);
        pk.z = f2bf(acc[i][j][2]);
        pk.w = f2bf(acc[i][j][3]);
        *reinterpret_cast<us4*>(&out[(size_t)(b * NH + h) * (DK * SEQ) + dd * SEQ + s0]) = pk;
      }
    }
  }
}

// ---------------- output-projection GEMM (f32 out) ----------------
__global__ __launch_bounds__(256) void gemm_o(const unsigned short* __restrict__ A,
                                              const unsigned short* __restrict__ B,
                                              float* __restrict__ out) {
  __shared__ __align__(16) unsigned short lA[128 * 32];
  __shared__ __align__(16) unsigned short lB[128 * 32];
  const int tid = threadIdx.x;
  const int lane = tid & 63;
  const int wid = tid >> 6;
  const int l15 = lane & 15, l4 = lane >> 4;
  const int bm = blockIdx.x, bn = blockIdx.y;
  const int wr = wid >> 1, wc = wid & 1;

  f32x4 acc[4][4] = {};

  const int chunk0 = (wid * 2 + 0) * 64 + lane;
  const int chunk1 = (wid * 2 + 1) * 64 + lane;
  const unsigned short* gA0 = A + (size_t)(bm * 128 + (chunk0 >> 2)) * 1024 + (chunk0 & 3) * 8;
  const unsigned short* gA1 = A + (size_t)(bm * 128 + (chunk1 >> 2)) * 1024 + (chunk1 & 3) * 8;
  const unsigned short* gB0 = B + (size_t)(bn * 128 + (chunk0 >> 2)) * 1024 + (chunk0 & 3) * 8;
  const unsigned short* gB1 = B + (size_t)(bn * 128 + (chunk1 >> 2)) * 1024 + (chunk1 & 3) * 8;
  unsigned short* lA0 = lA + (wid * 2 + 0) * 512;
  unsigned short* lA1 = lA + (wid * 2 + 1) * 512;
  unsigned short* lB0 = lB + (wid * 2 + 0) * 512;
  unsigned short* lB1 = lB + (wid * 2 + 1) * 512;

  for (int kt = 0; kt < 1024; kt += 32) {
    __syncthreads();
    gload16(gA0 + kt, lA0);
    gload16(gA1 + kt, lA1);
    gload16(gB0 + kt, lB0);
    gload16(gB1 + kt, lB1);
    __syncthreads();
    bf16x8 af[4], bfr[4];
#pragma unroll
    for (int i = 0; i < 4; ++i)
      af[i] = *reinterpret_cast<const bf16x8*>(&lA[(wr * 64 + i * 16 + l15) * 32 + l4 * 8]);
#pragma unroll
    for (int j = 0; j < 4; ++j)
      bfr[j] = *reinterpret_cast<const bf16x8*>(&lB[(wc * 64 + j * 16 + l15) * 32 + l4 * 8]);
#pragma unroll
    for (int i = 0; i < 4; ++i)
#pragma unroll
      for (int j = 0; j < 4; ++j)
        acc[i][j] = mfma_bf16(af[i], bfr[j], acc[i][j]);
  }

  const int row0 = bm * 128 + wr * 64;
  const int col0 = bn * 128 + wc * 64;
#pragma unroll
  for (int i = 0; i < 4; ++i)
#pragma unroll
    for (int j = 0; j < 4; ++j)
#pragma unroll
      for (int r = 0; r < 4; ++r) {
        const int m = row0 + i * 16 + l4 * 4 + r;
        const int n = col0 + j * 16 + l15;
        out[(size_t)m * DMODEL + n] = acc[i][j][r];
      }
}

// ---------------- causal flash attention v5 ----------------
// 256 blocks x 8 waves, 1 block/CU. Block handles q-tiles {15-x, x} sequentially
// => uniform 34 k-tile units/block (load-balanced with all blocks co-resident).
// XCD-affinity decode: 4 bh per XCD (2MB K/V, L2-resident).
// K/V 64x64 tiles staged via global_load_lds (pre-swizzled source), triple-buffered,
// distance-2 prefetch, counted vmcnt(2).
__global__ __launch_bounds__(512, 2) void attn_kernel(const unsigned short* __restrict__ Qh,
                                                      const unsigned short* __restrict__ Kh,
                                                      const unsigned short* __restrict__ Vt,
                                                      unsigned short* __restrict__ Mg) {
  __shared__ __align__(16) unsigned short Kl[3][64 * 64];
  __shared__ __align__(16) unsigned short Vl[3][64 * 64];

  const int tid = threadIdx.x;
  const int lane = tid & 63;
  const int w = tid >> 6;
  const int l15 = lane & 15, l4 = lane >> 4;

  // XCD-affinity decode (round-robin dispatch->XCD assumption, perf-only)
  const int d = blockIdx.x;           // 0..255
  const int xcd = d & 7;
  const int j = d >> 3;               // 0..31
  const int bh = (j >> 3) * 8 + xcd;  // 4 bh per XCD
  const int x = j & 7;                // pair index 0..7

  const unsigned short* Qb = Qh + (size_t)bh * SEQ * DK;
  const unsigned short* Kb = Kh + (size_t)bh * SEQ * DK;
  const unsigned short* Vb = Vt + (size_t)bh * DK * SEQ;
  const int bq = bh >> 4, hh = bh & 15;
  unsigned short* Mbase = Mg + (size_t)bq * SEQ * DMODEL + hh * DK;

  // staging lane constants: lane covers row (w*8 + lane/8), swizzled granule
  const int srow = lane >> 3;              // 0..7
  const int sswz = (lane & 7) ^ srow;      // source granule (involution)
  const unsigned short* KsrcB = Kb + (size_t)(w * 8 + srow) * DK + sswz * 8;
  const unsigned short* VsrcB = Vb + (size_t)(w * 8 + srow) * SEQ + sswz * 8;

  const int l7 = l15 & 7;

  const int taus[2] = {15 - x, x};

#pragma unroll 1
  for (int seg = 0; seg < 2; ++seg) {
    const int tau = taus[seg];
    const int qbase = tau * 128;
    const int q0w = qbase + w * 16;
    const int nt = 2 * tau + 2;

    // protect LDS buffers from the previous segment's readers
    __syncthreads();

    bf16x8 qf0 = *reinterpret_cast<const bf16x8*>(Qb + (size_t)(q0w + l15) * DK + l4 * 8);
    bf16x8 qf1 = *reinterpret_cast<const bf16x8*>(Qb + (size_t)(q0w + l15) * DK + 32 + l4 * 8);

    f32x4 o[4] = {};
    float mrow = -__builtin_inff();
    float lrow = 0.0f;

    // prologue: stage tiles 0,1 into bufs 0,1
    gload16(KsrcB, &Kl[0][w * 512]);
    gload16(VsrcB, &Vl[0][w * 512]);
    gload16(KsrcB + (size_t)64 * DK, &Kl[1][w * 512]);
    gload16(VsrcB + 64, &Vl[1][w * 512]);

    int bi = 0;  // buffer holding tile t
#pragma unroll 1
    for (int t = 0; t < nt; ++t) {
      const int kbase = t << 6;
      if (t + 1 < nt) {
        asm volatile("s_waitcnt vmcnt(2)" ::: "memory");
      } else {
        asm volatile("s_waitcnt vmcnt(0)" ::: "memory");
      }
      __builtin_amdgcn_sched_barrier(0);
      __builtin_amdgcn_s_barrier();
      __builtin_amdgcn_sched_barrier(0);

      // stage tile t+2 into buffer (t+2)%3 == (t-1)%3 (readers done: barrier above)
      if (t + 2 < nt) {
        const int pb = (bi == 0) ? 2 : bi - 1;
        gload16(KsrcB + (size_t)(kbase + 128) * DK, &Kl[pb][w * 512]);
        gload16(VsrcB + (kbase + 128), &Vl[pb][w * 512]);
      }

      if (kbase < q0w + 16) {  // wave-uniform causal skip
        const unsigned short* Kc = Kl[bi];
        const unsigned short* Vc = Vl[bi];

        // ---- S^T = K Q^T ----
        f32x4 sc[4];
#pragma unroll
        for (int c = 0; c < 4; ++c) {
          const int krow = c * 16 + l15;
          bf16x8 kf0 = *reinterpret_cast<const bf16x8*>(&Kc[krow * 64 + ((l4 ^ l7) * 8)]);
          bf16x8 kf1 = *reinterpret_cast<const bf16x8*>(&Kc[krow * 64 + (((4 + l4) ^ l7) * 8)]);
          f32x4 z = {0.f, 0.f, 0.f, 0.f};
          z = mfma_bf16(kf0, qf0, z);
          sc[c] = mfma_bf16(kf1, qf1, z);
        }

        // ---- causal mask (diagonal tiles only) ----
        if (kbase + 63 > q0w) {
          const int qg = q0w + l15;
#pragma unroll
          for (int c = 0; c < 4; ++c) {
            const int kp = kbase + c * 16 + l4 * 4;
#pragma unroll
            for (int r = 0; r < 4; ++r)
              if (kp + r > qg) sc[c][r] = -__builtin_inff();
          }
        }

        // ---- online softmax ----
        f32x4 mv = sc[0];
#pragma unroll
        for (int c = 1; c < 4; ++c)
#pragma unroll
          for (int r = 0; r < 4; ++r) mv[r] = fmaxf(mv[r], sc[c][r]);
        float pm = fmaxf(fmaxf(mv[0], mv[1]), fmaxf(mv[2], mv[3]));
        pm = fmaxf(pm, __shfl_xor(pm, 16));
        pm = fmaxf(pm, __shfl_xor(pm, 32));
        const float mn = fmaxf(mrow, pm);
        const float al = __builtin_amdgcn_exp2f(mrow - mn);
        mrow = mn;
        f32x4 sv = {0.f, 0.f, 0.f, 0.f};
        us4 pb4[4];
#pragma unroll
        for (int c = 0; c < 4; ++c) {
#pragma unroll
          for (int r = 0; r < 4; ++r) {
            const float p = __builtin_amdgcn_exp2f(sc[c][r] - mn);
            sc[c][r] = p;
            sv[r] += p;
          }
          us4 pk;
          pk.x = f2bf(sc[c][0]);
          pk.y = f2bf(sc[c][1]);
          pk.z = f2bf(sc[c][2]);
          pk.w = f2bf(sc[c][3]);
          pb4[c] = pk;
        }
        float rs = (sv[0] + sv[1]) + (sv[2] + sv[3]);
        rs += __shfl_xor(rs, 16);
        rs += __shfl_xor(rs, 32);
        lrow = lrow * al + rs;
#pragma unroll
        for (int dd = 0; dd < 4; ++dd)
#pragma unroll
          for (int r = 0; r < 4; ++r) o[dd][r] *= al;

        // ---- O^T += V^T P ----
#pragma unroll
        for (int dd = 0; dd < 4; ++dd) {
          const int vrow = dd * 16 + l15;
#pragma unroll
          for (int c = 0; c < 4; ++c) {
            const us4 va = *reinterpret_cast<const us4*>(
                &Vc[vrow * 64 + (((c * 2 + (l4 >> 1)) ^ l7) * 8) + (l4 & 1) * 4]);
            o[dd] = mfma_k16(va, pb4[c], o[dd]);
          }
        }
      }

      bi = (bi == 2) ? 0 : bi + 1;
    }

    // ---- epilogue ----
    const float inv = __builtin_amdgcn_rcpf(lrow);
    const int s = q0w + l15;
#pragma unroll
    for (int dd = 0; dd < 4; ++dd) {
      us4 pk;
      pk.x = f2bf(o[dd][0] * inv);
      pk.y = f2bf(o[dd][1] * inv);
      pk.z = f2bf(o[dd][2] * inv);
      pk.w = f2bf(o[dd][3] * inv);
      *reinterpret_cast<us4*>(&Mbase[(size_t)s * DMODEL + dd * 16 + l4 * 4]) = pk;
    }
  }
}

extern "C" void kernel_launch(void* const* d_in, const int* in_sizes, int n_in,
                              void* d_out, int out_size, void* d_ws, size_t ws_size,
                              hipStream_t stream) {
  (void)in_sizes; (void)n_in; (void)out_size;
  if (ws_size < (size_t)64 * (1 << 20)) return;  // need 64MB scratch

  const float* q = (const float*)d_in[0];
  const float* k = (const float*)d_in[1];
  const float* v = (const float*)d_in[2];
  // d_in[3] = mask (causal, hardcoded)
  const float* wq = (const float*)d_in[4];
  const float* wk = (const float*)d_in[5];
  const float* wv = (const float*)d_in[6];
  const float* wo = (const float*)d_in[7];

  char* ws = (char*)d_ws;
  unsigned short* xq  = (unsigned short*)(ws + (size_t)0  * (1 << 20));
  unsigned short* xk  = (unsigned short*)(ws + (size_t)8  * (1 << 20));
  unsigned short* xv  = (unsigned short*)(ws + (size_t)16 * (1 << 20));
  unsigned short* bwq = (unsigned short*)(ws + (size_t)24 * (1 << 20));
  unsigned short* bwk = (unsigned short*)(ws + (size_t)26 * (1 << 20));
  unsigned short* bwv = (unsigned short*)(ws + (size_t)28 * (1 << 20));
  unsigned short* bwo = (unsigned short*)(ws + (size_t)30 * (1 << 20));
  unsigned short* Qh  = (unsigned short*)(ws + (size_t)32 * (1 << 20));
  unsigned short* Kh  = (unsigned short*)(ws + (size_t)40 * (1 << 20));
  unsigned short* Vt  = (unsigned short*)(ws + (size_t)48 * (1 << 20));
  unsigned short* Mg  = (unsigned short*)(ws + (size_t)56 * (1 << 20));

  cvt_all<<<dim3(256, 7), 256, 0, stream>>>(q, k, v, wq, wk, wv, wo,
                                            xq, xk, xv, bwq, bwk, bwv, bwo);
  gemm_qkv<<<dim3(32, 8, 3), 256, 0, stream>>>(xq, xk, xv, bwq, bwk, bwv, Qh, Kh, Vt);
  attn_kernel<<<dim3(256), 512, 0, stream>>>(Qh, Kh, Vt, Mg);
  gemm_o<<<dim3(32, 8), 256, 0, stream>>>(Mg, bwo, (float*)d_out);
}

// Round 6
// 135.733 us; speedup vs baseline: 2.4917x; 1.0698x over previous
//
#include <hip/hip_runtime.h>
#include <hip/hip_bf16.h>
#include <stdint.h>

typedef __attribute__((ext_vector_type(4))) float f32x4;
typedef __attribute__((ext_vector_type(8))) __bf16 bf16x8;
typedef __attribute__((ext_vector_type(4))) unsigned short us4;

#define SEQ 2048
#define DMODEL 1024
#define NH 16
#define DK 64
#define MTOT 4096  // B*SEQ

__device__ __forceinline__ unsigned short f2bf(float x) {
  union { float f; unsigned int u; } v; v.f = x;
  unsigned int r = v.u + 0x7fffu + ((v.u >> 16) & 1u);
  return (unsigned short)(r >> 16);
}

// pack 2 f32 -> 2 bf16 in one u32 (lo, hi)
__device__ __forceinline__ unsigned int cvtpk(float lo, float hi) {
  unsigned int r;
  asm("v_cvt_pk_bf16_f32 %0, %1, %2" : "=v"(r) : "v"(lo), "v"(hi));
  return r;
}

__device__ __forceinline__ f32x4 mfma_bf16(bf16x8 a, bf16x8 b, f32x4 c) {
  return __builtin_amdgcn_mfma_f32_16x16x32_bf16(a, b, c, 0, 0, 0);
}

__device__ __forceinline__ void gload16(const unsigned short* g, unsigned short* l) {
  __builtin_amdgcn_global_load_lds((__attribute__((address_space(1))) void*)g,
                                   (__attribute__((address_space(3))) void*)l,
                                   16, 0, 0);
}

// ---------------- fp32 -> bf16 conversion (all 7 tensors, one launch) ----------------
__global__ void cvt_all(const float* __restrict__ s0, const float* __restrict__ s1,
                        const float* __restrict__ s2, const float* __restrict__ s3,
                        const float* __restrict__ s4, const float* __restrict__ s5,
                        const float* __restrict__ s6,
                        unsigned short* __restrict__ d0, unsigned short* __restrict__ d1,
                        unsigned short* __restrict__ d2, unsigned short* __restrict__ d3,
                        unsigned short* __restrict__ d4, unsigned short* __restrict__ d5,
                        unsigned short* __restrict__ d6) {
  const int y = blockIdx.y;
  const float* s = y == 0 ? s0 : y == 1 ? s1 : y == 2 ? s2 : y == 3 ? s3
                 : y == 4 ? s4 : y == 5 ? s5 : s6;
  unsigned short* d = y == 0 ? d0 : y == 1 ? d1 : y == 2 ? d2 : y == 3 ? d3
                    : y == 4 ? d4 : y == 5 ? d5 : d6;
  const int n4 = (y < 3) ? (MTOT * DMODEL / 4) : (DMODEL * DMODEL / 4);
  const int stride = gridDim.x * blockDim.x;
  for (int i = blockIdx.x * blockDim.x + threadIdx.x; i < n4; i += stride) {
    f32x4 v = reinterpret_cast<const f32x4*>(s)[i];
    us4 o;
    o.x = f2bf(v.x); o.y = f2bf(v.y); o.z = f2bf(v.z); o.w = f2bf(v.w);
    reinterpret_cast<us4*>(d)[i] = o;
  }
}

// ---------------- fused QKV GEMM: C[m,n] = sum_k A[m,k]*B[n,k], K=1024 ----------------
// z=0: Q (head layout, scaled), z=1: K (head layout), z=2: V (V^T layout, PV-permuted)
__global__ __launch_bounds__(256) void gemm_qkv(
    const unsigned short* __restrict__ xq, const unsigned short* __restrict__ xk,
    const unsigned short* __restrict__ xv, const unsigned short* __restrict__ bwq,
    const unsigned short* __restrict__ bwk, const unsigned short* __restrict__ bwv,
    unsigned short* __restrict__ Qh, unsigned short* __restrict__ Kh,
    unsigned short* __restrict__ Vt) {
  const int z = blockIdx.z;
  const unsigned short* A = z == 0 ? xq : (z == 1 ? xk : xv);
  const unsigned short* B = z == 0 ? bwq : (z == 1 ? bwk : bwv);
  unsigned short* out = z == 0 ? Qh : (z == 1 ? Kh : Vt);
  const float scale = z == 0 ? 0.18033688011112042f : 1.0f;  // (1/8)*log2(e) for Q

  __shared__ __align__(16) unsigned short lA[128 * 32];
  __shared__ __align__(16) unsigned short lB[128 * 32];
  const int tid = threadIdx.x;
  const int lane = tid & 63;
  const int wid = tid >> 6;
  const int l15 = lane & 15, l4 = lane >> 4;
  const int bm = blockIdx.x, bn = blockIdx.y;
  const int wr = wid >> 1, wc = wid & 1;

  f32x4 acc[4][4] = {};

  const int chunk0 = (wid * 2 + 0) * 64 + lane;
  const int chunk1 = (wid * 2 + 1) * 64 + lane;
  const unsigned short* gA0 = A + (size_t)(bm * 128 + (chunk0 >> 2)) * 1024 + (chunk0 & 3) * 8;
  const unsigned short* gA1 = A + (size_t)(bm * 128 + (chunk1 >> 2)) * 1024 + (chunk1 & 3) * 8;
  const unsigned short* gB0 = B + (size_t)(bn * 128 + (chunk0 >> 2)) * 1024 + (chunk0 & 3) * 8;
  const unsigned short* gB1 = B + (size_t)(bn * 128 + (chunk1 >> 2)) * 1024 + (chunk1 & 3) * 8;
  unsigned short* lA0 = lA + (wid * 2 + 0) * 512;
  unsigned short* lA1 = lA + (wid * 2 + 1) * 512;
  unsigned short* lB0 = lB + (wid * 2 + 0) * 512;
  unsigned short* lB1 = lB + (wid * 2 + 1) * 512;

  for (int kt = 0; kt < 1024; kt += 32) {
    __syncthreads();
    gload16(gA0 + kt, lA0);
    gload16(gA1 + kt, lA1);
    gload16(gB0 + kt, lB0);
    gload16(gB1 + kt, lB1);
    __syncthreads();
    bf16x8 af[4], bfr[4];
#pragma unroll
    for (int i = 0; i < 4; ++i)
      af[i] = *reinterpret_cast<const bf16x8*>(&lA[(wr * 64 + i * 16 + l15) * 32 + l4 * 8]);
#pragma unroll
    for (int j = 0; j < 4; ++j)
      bfr[j] = *reinterpret_cast<const bf16x8*>(&lB[(wc * 64 + j * 16 + l15) * 32 + l4 * 8]);
#pragma unroll
    for (int i = 0; i < 4; ++i)
#pragma unroll
      for (int j = 0; j < 4; ++j)
        acc[i][j] = mfma_bf16(af[i], bfr[j], acc[i][j]);
  }

  const int row0 = bm * 128 + wr * 64;
  const int col0 = bn * 128 + wc * 64;

  if (z < 2) {
#pragma unroll
    for (int i = 0; i < 4; ++i) {
#pragma unroll
      for (int j = 0; j < 4; ++j) {
        const int n = col0 + j * 16 + l15;
        const int h = n >> 6, dd = n & 63;
#pragma unroll
        for (int r = 0; r < 4; ++r) {
          const int m = row0 + i * 16 + l4 * 4 + r;
          const int b = m >> 11, s = m & 2047;
          out[(size_t)(b * NH + h) * (SEQ * DK) + s * DK + dd] = f2bf(acc[i][j][r] * scale);
        }
      }
    }
  } else {
    // V^T with per-32-col PV permutation: 4-group g of each 32-chunk stored at
    // (g&3)*8 + (g>>2)*4 so a b128 read yields a legal K=32 B/A fragment pair.
#pragma unroll
    for (int i = 0; i < 4; ++i) {
      const int m0 = row0 + i * 16 + l4 * 4;
      const int b = m0 >> 11, s0 = m0 & 2047;
      const int g = (s0 >> 2) & 7;
      const int col = (s0 & ~31) + ((g & 3) << 3) + ((g >> 2) << 2);
#pragma unroll
      for (int j = 0; j < 4; ++j) {
        const int n = col0 + j * 16 + l15;
        const int h = n >> 6, dd = n & 63;
        us4 pk;
        pk.x = f2bf(acc[i][j][0]);
        pk.y = f2bf(acc[i][j][1]);
        pk.z = f2bf(acc[i][j][2]);
        pk.w = f2bf(acc[i][j][3]);
        *reinterpret_cast<us4*>(&out[(size_t)(b * NH + h) * (DK * SEQ) + dd * SEQ + col]) = pk;
      }
    }
  }
}

// ---------------- output-projection GEMM (f32 out) ----------------
__global__ __launch_bounds__(256) void gemm_o(const unsigned short* __restrict__ A,
                                              const unsigned short* __restrict__ B,
                                              float* __restrict__ out) {
  __shared__ __align__(16) unsigned short lA[128 * 32];
  __shared__ __align__(16) unsigned short lB[128 * 32];
  const int tid = threadIdx.x;
  const int lane = tid & 63;
  const int wid = tid >> 6;
  const int l15 = lane & 15, l4 = lane >> 4;
  const int bm = blockIdx.x, bn = blockIdx.y;
  const int wr = wid >> 1, wc = wid & 1;

  f32x4 acc[4][4] = {};

  const int chunk0 = (wid * 2 + 0) * 64 + lane;
  const int chunk1 = (wid * 2 + 1) * 64 + lane;
  const unsigned short* gA0 = A + (size_t)(bm * 128 + (chunk0 >> 2)) * 1024 + (chunk0 & 3) * 8;
  const unsigned short* gA1 = A + (size_t)(bm * 128 + (chunk1 >> 2)) * 1024 + (chunk1 & 3) * 8;
  const unsigned short* gB0 = B + (size_t)(bn * 128 + (chunk0 >> 2)) * 1024 + (chunk0 & 3) * 8;
  const unsigned short* gB1 = B + (size_t)(bn * 128 + (chunk1 >> 2)) * 1024 + (chunk1 & 3) * 8;
  unsigned short* lA0 = lA + (wid * 2 + 0) * 512;
  unsigned short* lA1 = lA + (wid * 2 + 1) * 512;
  unsigned short* lB0 = lB + (wid * 2 + 0) * 512;
  unsigned short* lB1 = lB + (wid * 2 + 1) * 512;

  for (int kt = 0; kt < 1024; kt += 32) {
    __syncthreads();
    gload16(gA0 + kt, lA0);
    gload16(gA1 + kt, lA1);
    gload16(gB0 + kt, lB0);
    gload16(gB1 + kt, lB1);
    __syncthreads();
    bf16x8 af[4], bfr[4];
#pragma unroll
    for (int i = 0; i < 4; ++i)
      af[i] = *reinterpret_cast<const bf16x8*>(&lA[(wr * 64 + i * 16 + l15) * 32 + l4 * 8]);
#pragma unroll
    for (int j = 0; j < 4; ++j)
      bfr[j] = *reinterpret_cast<const bf16x8*>(&lB[(wc * 64 + j * 16 + l15) * 32 + l4 * 8]);
#pragma unroll
    for (int i = 0; i < 4; ++i)
#pragma unroll
      for (int j = 0; j < 4; ++j)
        acc[i][j] = mfma_bf16(af[i], bfr[j], acc[i][j]);
  }

  const int row0 = bm * 128 + wr * 64;
  const int col0 = bn * 128 + wc * 64;
#pragma unroll
  for (int i = 0; i < 4; ++i)
#pragma unroll
    for (int j = 0; j < 4; ++j)
#pragma unroll
      for (int r = 0; r < 4; ++r) {
        const int m = row0 + i * 16 + l4 * 4 + r;
        const int n = col0 + j * 16 + l15;
        out[(size_t)m * DMODEL + n] = acc[i][j][r];
      }
}

// ---------------- causal flash attention v6 ----------------
// v5 skeleton (256 blocks x 8 waves, {15-x,x} pairing, XCD affinity, triple-buffer
// dist-2 prefetch) + fused K=32 PV (permuted V), defer-max softmax (T13),
// v_cvt_pk_bf16_f32 packing, setprio around MFMA clusters.
__global__ __launch_bounds__(512, 2) void attn_kernel(const unsigned short* __restrict__ Qh,
                                                      const unsigned short* __restrict__ Kh,
                                                      const unsigned short* __restrict__ Vt,
                                                      unsigned short* __restrict__ Mg) {
  __shared__ __align__(16) unsigned short Kl[3][64 * 64];
  __shared__ __align__(16) unsigned short Vl[3][64 * 64];

  const int tid = threadIdx.x;
  const int lane = tid & 63;
  const int w = tid >> 6;
  const int l15 = lane & 15, l4 = lane >> 4;

  // XCD-affinity decode (round-robin dispatch->XCD assumption, perf-only)
  const int d = blockIdx.x;           // 0..255
  const int xcd = d & 7;
  const int j = d >> 3;               // 0..31
  const int bh = (j >> 3) * 8 + xcd;  // 4 bh per XCD
  const int x = j & 7;                // pair index 0..7

  const unsigned short* Qb = Qh + (size_t)bh * SEQ * DK;
  const unsigned short* Kb = Kh + (size_t)bh * SEQ * DK;
  const unsigned short* Vb = Vt + (size_t)bh * DK * SEQ;
  const int bq = bh >> 4, hh = bh & 15;
  unsigned short* Mbase = Mg + (size_t)bq * SEQ * DMODEL + hh * DK;

  // staging lane constants: lane covers row (w*8 + srow), swizzled granule
  const int srow = lane >> 3;              // 0..7
  const int sswz = (lane & 7) ^ srow;      // source granule (involution)
  const unsigned short* KsrcB = Kb + (size_t)(w * 8 + srow) * DK + sswz * 8;
  const unsigned short* VsrcB = Vb + (size_t)(w * 8 + srow) * SEQ + sswz * 8;

  const int l7 = l15 & 7;

  const int taus[2] = {15 - x, x};

#pragma unroll 1
  for (int seg = 0; seg < 2; ++seg) {
    const int tau = taus[seg];
    const int qbase = tau * 128;
    const int q0w = qbase + w * 16;
    const int nt = 2 * tau + 2;

    // protect LDS buffers from the previous segment's readers
    __syncthreads();

    bf16x8 qf0 = *reinterpret_cast<const bf16x8*>(Qb + (size_t)(q0w + l15) * DK + l4 * 8);
    bf16x8 qf1 = *reinterpret_cast<const bf16x8*>(Qb + (size_t)(q0w + l15) * DK + 32 + l4 * 8);

    f32x4 o[4] = {};
    float mrow = -__builtin_inff();
    float lrow = 0.0f;  // per-lane partial; cross-lane summed in epilogue

    // prologue: stage tiles 0,1 into bufs 0,1
    gload16(KsrcB, &Kl[0][w * 512]);
    gload16(VsrcB, &Vl[0][w * 512]);
    gload16(KsrcB + (size_t)64 * DK, &Kl[1][w * 512]);
    gload16(VsrcB + 64, &Vl[1][w * 512]);

    int bi = 0;  // buffer holding tile t
#pragma unroll 1
    for (int t = 0; t < nt; ++t) {
      const int kbase = t << 6;
      if (t + 1 < nt) {
        asm volatile("s_waitcnt vmcnt(2)" ::: "memory");
      } else {
        asm volatile("s_waitcnt vmcnt(0)" ::: "memory");
      }
      __builtin_amdgcn_sched_barrier(0);
      __builtin_amdgcn_s_barrier();
      __builtin_amdgcn_sched_barrier(0);

      // stage tile t+2 into buffer (t-1)%3 (its readers are done: barrier above)
      if (t + 2 < nt) {
        const int pb = (bi == 0) ? 2 : bi - 1;
        gload16(KsrcB + (size_t)(kbase + 128) * DK, &Kl[pb][w * 512]);
        gload16(VsrcB + (kbase + 128), &Vl[pb][w * 512]);
      }

      if (kbase < q0w + 16) {  // wave-uniform causal skip
        const unsigned short* Kc = Kl[bi];
        const unsigned short* Vc = Vl[bi];

        // ---- S^T = K Q^T ----
        f32x4 sc[4];
        __builtin_amdgcn_s_setprio(1);
#pragma unroll
        for (int c = 0; c < 4; ++c) {
          const int krow = c * 16 + l15;
          bf16x8 kf0 = *reinterpret_cast<const bf16x8*>(&Kc[krow * 64 + ((l4 ^ l7) * 8)]);
          bf16x8 kf1 = *reinterpret_cast<const bf16x8*>(&Kc[krow * 64 + (((4 + l4) ^ l7) * 8)]);
          f32x4 z = {0.f, 0.f, 0.f, 0.f};
          z = mfma_bf16(kf0, qf0, z);
          sc[c] = mfma_bf16(kf1, qf1, z);
        }
        __builtin_amdgcn_s_setprio(0);

        // ---- causal mask (diagonal tiles only) ----
        if (kbase + 63 > q0w) {
          const int qg = q0w + l15;
#pragma unroll
          for (int c = 0; c < 4; ++c) {
            const int kp = kbase + c * 16 + l4 * 4;
#pragma unroll
            for (int r = 0; r < 4; ++r)
              if (kp + r > qg) sc[c][r] = -__builtin_inff();
          }
        }

        // ---- online softmax with defer-max (T13, log2 domain, THR=8) ----
        f32x4 mv = sc[0];
#pragma unroll
        for (int c = 1; c < 4; ++c)
#pragma unroll
          for (int r = 0; r < 4; ++r) mv[r] = fmaxf(mv[r], sc[c][r]);
        float pm = fmaxf(fmaxf(mv[0], mv[1]), fmaxf(mv[2], mv[3]));
        if (!__all(pm - mrow <= 8.0f)) {
          pm = fmaxf(pm, __shfl_xor(pm, 16));
          pm = fmaxf(pm, __shfl_xor(pm, 32));
          const float mn = fmaxf(mrow, pm);
          const float al = __builtin_amdgcn_exp2f(mrow - mn);
          mrow = mn;
          lrow *= al;
#pragma unroll
          for (int dd = 0; dd < 4; ++dd)
#pragma unroll
            for (int r = 0; r < 4; ++r) o[dd][r] *= al;
        }
        // P = exp2(S - mrow); pack straight into K=32 B-fragments
        union PB { bf16x8 v; unsigned int u[4]; } pbv[2];
        f32x4 sv = {0.f, 0.f, 0.f, 0.f};
#pragma unroll
        for (int c = 0; c < 4; ++c) {
          const float p0 = __builtin_amdgcn_exp2f(sc[c][0] - mrow);
          const float p1 = __builtin_amdgcn_exp2f(sc[c][1] - mrow);
          const float p2 = __builtin_amdgcn_exp2f(sc[c][2] - mrow);
          const float p3 = __builtin_amdgcn_exp2f(sc[c][3] - mrow);
          sv[0] += p0; sv[1] += p1; sv[2] += p2; sv[3] += p3;
          pbv[c >> 1].u[(c & 1) * 2 + 0] = cvtpk(p0, p1);
          pbv[c >> 1].u[(c & 1) * 2 + 1] = cvtpk(p2, p3);
        }
        lrow += (sv[0] + sv[1]) + (sv[2] + sv[3]);

        // ---- O^T += V^T P  (fused K=32; V pre-permuted) ----
        __builtin_amdgcn_s_setprio(1);
#pragma unroll
        for (int dd = 0; dd < 4; ++dd) {
          const int vrow = dd * 16 + l15;
#pragma unroll
          for (int p = 0; p < 2; ++p) {
            const bf16x8 av = *reinterpret_cast<const bf16x8*>(
                &Vc[vrow * 64 + (((p * 4 + l4) ^ l7) * 8)]);
            o[dd] = mfma_bf16(av, pbv[p].v, o[dd]);
          }
        }
        __builtin_amdgcn_s_setprio(0);
      }

      bi = (bi == 2) ? 0 : bi + 1;
    }

    // ---- epilogue: cross-lane lrow sum, normalize, pack, store ----
    lrow += __shfl_xor(lrow, 16);
    lrow += __shfl_xor(lrow, 32);
    const float inv = __builtin_amdgcn_rcpf(lrow);
    const int s = q0w + l15;
#pragma unroll
    for (int dd = 0; dd < 4; ++dd) {
      union { us4 h; unsigned int u[2]; } pk;
      pk.u[0] = cvtpk(o[dd][0] * inv, o[dd][1] * inv);
      pk.u[1] = cvtpk(o[dd][2] * inv, o[dd][3] * inv);
      *reinterpret_cast<us4*>(&Mbase[(size_t)s * DMODEL + dd * 16 + l4 * 4]) = pk.h;
    }
  }
}

extern "C" void kernel_launch(void* const* d_in, const int* in_sizes, int n_in,
                              void* d_out, int out_size, void* d_ws, size_t ws_size,
                              hipStream_t stream) {
  (void)in_sizes; (void)n_in; (void)out_size;
  if (ws_size < (size_t)64 * (1 << 20)) return;  // need 64MB scratch

  const float* q = (const float*)d_in[0];
  const float* k = (const float*)d_in[1];
  const float* v = (const float*)d_in[2];
  // d_in[3] = mask (causal, hardcoded)
  const float* wq = (const float*)d_in[4];
  const float* wk = (const float*)d_in[5];
  const float* wv = (const float*)d_in[6];
  const float* wo = (const float*)d_in[7];

  char* ws = (char*)d_ws;
  unsigned short* xq  = (unsigned short*)(ws + (size_t)0  * (1 << 20));
  unsigned short* xk  = (unsigned short*)(ws + (size_t)8  * (1 << 20));
  unsigned short* xv  = (unsigned short*)(ws + (size_t)16 * (1 << 20));
  unsigned short* bwq = (unsigned short*)(ws + (size_t)24 * (1 << 20));
  unsigned short* bwk = (unsigned short*)(ws + (size_t)26 * (1 << 20));
  unsigned short* bwv = (unsigned short*)(ws + (size_t)28 * (1 << 20));
  unsigned short* bwo = (unsigned short*)(ws + (size_t)30 * (1 << 20));
  unsigned short* Qh  = (unsigned short*)(ws + (size_t)32 * (1 << 20));
  unsigned short* Kh  = (unsigned short*)(ws + (size_t)40 * (1 << 20));
  unsigned short* Vt  = (unsigned short*)(ws + (size_t)48 * (1 << 20));
  unsigned short* Mg  = (unsigned short*)(ws + (size_t)56 * (1 << 20));

  cvt_all<<<dim3(256, 7), 256, 0, stream>>>(q, k, v, wq, wk, wv, wo,
                                            xq, xk, xv, bwq, bwk, bwv, bwo);
  gemm_qkv<<<dim3(32, 8, 3), 256, 0, stream>>>(xq, xk, xv, bwq, bwk, bwv, Qh, Kh, Vt);
  attn_kernel<<<dim3(256), 512, 0, stream>>>(Qh, Kh, Vt, Mg);
  gemm_o<<<dim3(32, 8), 256, 0, stream>>>(Mg, bwo, (float*)d_out);
}